// Round 7
// baseline (937.572 us; speedup 1.0000x reference)
//
#include <hip/hip_runtime.h>
#include <hip/hip_bf16.h>

#define HID     256
#define NNODES  50000
#define NEDGES  300000
#define NGRAPHS 128
#define L       4

typedef __attribute__((ext_vector_type(8))) short bf16x8;
typedef __attribute__((ext_vector_type(4))) float f32x4;
typedef __attribute__((ext_vector_type(4))) unsigned short u16x4;
typedef __attribute__((ext_vector_type(8))) unsigned short u16x8;

static __device__ __forceinline__ float b2f(unsigned short s) {
    union { unsigned u; float f; } v;
    v.u = ((unsigned)s) << 16;
    return v.f;
}
static __device__ __forceinline__ short f2b(float f) {
    __hip_bfloat16 h = __float2bfloat16(f);
    return *reinterpret_cast<short*>(&h);
}

// ------------------------------------------------ weight convert + transpose
__global__ void wconv_k(const float* __restrict__ w, short* __restrict__ wT) {
    int m = blockIdx.y, n = blockIdx.x, k = threadIdx.x;
    wT[(size_t)m * 65536 + n * 256 + k] = f2b(w[(size_t)m * 65536 + k * 256 + n]);
}

// ---------------------------------------------------------------- node embed
__global__ void node_embed_k(const float* __restrict__ x,
                             const float* __restrict__ w,
                             const float* __restrict__ b,
                             short* __restrict__ hb) {
    int n = blockIdx.x;
    int j = threadIdx.x;
    __shared__ float xr[32];
    if (j < 32) xr[j] = x[n * 32 + j];
    __syncthreads();
    float acc = b[j];
#pragma unroll
    for (int k = 0; k < 32; ++k) acc = fmaf(xr[k], w[k * HID + j], acc);
    hb[(size_t)n * HID + j] = f2b(acc);
}

// ------------------------------------------------------------- CSR building
__global__ void deg_k(const int* __restrict__ ei, int* __restrict__ deg) {
    int e = blockIdx.x * 256 + threadIdx.x;
    if (e < NEDGES) atomicAdd(&deg[ei[NEDGES + e]], 1);
}

__global__ void scan1_k(const int* __restrict__ deg, int* __restrict__ partial,
                        int* __restrict__ btot) {
    __shared__ int s[256];
    int t = threadIdx.x;
    int gi = blockIdx.x * 256 + t;
    s[t] = (gi < NNODES) ? deg[gi] : 0;
    __syncthreads();
    for (int off = 1; off < 256; off <<= 1) {
        int u = (t >= off) ? s[t - off] : 0;
        __syncthreads();
        s[t] += u;
        __syncthreads();
    }
    if (gi < NNODES) partial[gi] = s[t];
    if (t == 255) btot[blockIdx.x] = s[255];
}

__global__ void scan2_k(int* __restrict__ btot, int nb) {
    __shared__ int s[256];
    int t = threadIdx.x;
    s[t] = (t < nb) ? btot[t] : 0;
    __syncthreads();
    for (int off = 1; off < 256; off <<= 1) {
        int u = (t >= off) ? s[t - off] : 0;
        __syncthreads();
        s[t] += u;
        __syncthreads();
    }
    btot[t] = s[t];
}

__global__ void scan3_k(const int* __restrict__ deg, const int* __restrict__ partial,
                        const int* __restrict__ btot, int* __restrict__ row_ptr,
                        int* __restrict__ cursor) {
    int gi = blockIdx.x * 256 + threadIdx.x;
    if (gi >= NNODES) return;
    int b = blockIdx.x;
    int incl = partial[gi] + (b ? btot[b - 1] : 0);
    int start = incl - deg[gi];
    row_ptr[gi] = start;
    cursor[gi] = start;
    if (gi == NNODES - 1) row_ptr[NNODES] = incl;
}

__global__ void fill_k(const int* __restrict__ ei, int* __restrict__ cursor,
                       int* __restrict__ eid) {
    int e = blockIdx.x * 256 + threadIdx.x;
    if (e < NEDGES) {
        int d = ei[NEDGES + e];
        int pos = atomicAdd(&cursor[d], 1);
        eid[pos] = e;
    }
}

// ---------- one-time: slot-ordered bf16 eattr (32B/edge) + srcs
__global__ void esort2_k(const float* __restrict__ eattr, const int* __restrict__ ei,
                         const int* __restrict__ eid, short* __restrict__ eattr_bs,
                         int* __restrict__ srcs) {
    int t = blockIdx.x * 256 + threadIdx.x;
    if (t >= NEDGES) return;
    int e = eid[t];
    const float4* ep = reinterpret_cast<const float4*>(eattr + (size_t)e * 16);
    float4 q0 = ep[0], q1 = ep[1], q2 = ep[2], q3 = ep[3];
    u16x8 o0, o1;
    o0[0] = (unsigned short)f2b(q0.x); o0[1] = (unsigned short)f2b(q0.y);
    o0[2] = (unsigned short)f2b(q0.z); o0[3] = (unsigned short)f2b(q0.w);
    o0[4] = (unsigned short)f2b(q1.x); o0[5] = (unsigned short)f2b(q1.y);
    o0[6] = (unsigned short)f2b(q1.z); o0[7] = (unsigned short)f2b(q1.w);
    o1[0] = (unsigned short)f2b(q2.x); o1[1] = (unsigned short)f2b(q2.y);
    o1[2] = (unsigned short)f2b(q2.z); o1[3] = (unsigned short)f2b(q2.w);
    o1[4] = (unsigned short)f2b(q3.x); o1[5] = (unsigned short)f2b(q3.y);
    o1[6] = (unsigned short)f2b(q3.z); o1[7] = (unsigned short)f2b(q3.w);
    u16x8* op = reinterpret_cast<u16x8*>(eattr_bs + (size_t)t * 16);
    op[0] = o0; op[1] = o1;
    srcs[t] = ei[e];
}

// ------------------------------------------------- fused CSR aggregate
// zb[n] = hb[n] + sum_t relu(hb[srcs[t]] + eattr_bs[t]@ew + eb)
// Wave owns 4 consecutive nodes; window of 4 edges in flight; ea computed
// on the fly (edge_w held in 64 VGPRs). Block 0 zeroes BN stats.
#define AGG_NPW 4
#define AGG_W 4
__global__ __launch_bounds__(256) void agg_k(
    const short* __restrict__ hb, const short* __restrict__ eattr_bs,
    const int* __restrict__ srcs, const int* __restrict__ row_ptr,
    const float* __restrict__ ew, const float* __restrict__ ebias,
    short* __restrict__ zb, float* __restrict__ stats) {
    if (blockIdx.x == 0) {
        stats[threadIdx.x] = 0.f;
        stats[threadIdx.x + 256] = 0.f;
    }
    int lane = threadIdx.x & 63, wv = threadIdx.x >> 6;
    int c = lane * 4;
    float ewv[16][4];
#pragma unroll
    for (int k = 0; k < 16; ++k) {
        float4 v = *reinterpret_cast<const float4*>(ew + k * 256 + c);
        ewv[k][0] = v.x; ewv[k][1] = v.y; ewv[k][2] = v.z; ewv[k][3] = v.w;
    }
    float4 ebv = *reinterpret_cast<const float4*>(ebias + c);

    int n0 = (blockIdx.x * 4 + wv) * AGG_NPW;   // grid exact: 3125*16 = 50000
    int t    = row_ptr[n0];
    int tEnd = row_ptr[n0 + AGG_NPW];
    int nextB = row_ptr[n0 + 1];
    int n = 0;
    u16x4 hcur = *reinterpret_cast<const u16x4*>(hb + (size_t)n0 * HID + c);
    u16x4 hnxt = *reinterpret_cast<const u16x4*>(hb + (size_t)(n0 + 1) * HID + c);
    float a0 = 0.f, a1 = 0.f, a2 = 0.f, a3 = 0.f;

#define AGG_FLUSH()                                                          \
    do {                                                                     \
        u16x4 o_;                                                            \
        o_[0] = (unsigned short)f2b(a0 + b2f(hcur[0]));                      \
        o_[1] = (unsigned short)f2b(a1 + b2f(hcur[1]));                      \
        o_[2] = (unsigned short)f2b(a2 + b2f(hcur[2]));                      \
        o_[3] = (unsigned short)f2b(a3 + b2f(hcur[3]));                      \
        *reinterpret_cast<u16x4*>(zb + (size_t)(n0 + n) * HID + c) = o_;     \
        hcur = hnxt;                                                         \
        int pn_ = n0 + n + 2;                                                \
        if (pn_ < NNODES)                                                    \
            hnxt = *reinterpret_cast<const u16x4*>(hb + (size_t)pn_ * HID + c); \
        a0 = a1 = a2 = a3 = 0.f;                                             \
        ++n;                                                                 \
        nextB = row_ptr[min(n0 + n + 1, NNODES)];                            \
    } while (0)

    while (true) {
        while (n < AGG_NPW && t == nextB) AGG_FLUSH();
        if (n >= AGG_NPW) break;
        int m = min(AGG_W, tEnd - t);
        int ss[AGG_W] = {0, 0, 0, 0};
        u16x8 e0[AGG_W], e1[AGG_W];
        u16x4 gv[AGG_W];
#pragma unroll
        for (int k = 0; k < AGG_W; ++k)
            if (k < m) ss[k] = srcs[t + k];
#pragma unroll
        for (int k = 0; k < AGG_W; ++k)
            if (k < m) {
                const u16x8* ep = reinterpret_cast<const u16x8*>(eattr_bs + (size_t)(t + k) * 16);
                e0[k] = ep[0]; e1[k] = ep[1];
                gv[k] = *reinterpret_cast<const u16x4*>(hb + (size_t)ss[k] * HID + c);
            }
#pragma unroll
        for (int k = 0; k < AGG_W; ++k) {
            if (k < m) {
                while (n < AGG_NPW && t + k == nextB) AGG_FLUSH();
                float ek[16];
#pragma unroll
                for (int j = 0; j < 8; ++j) {
                    ek[j]     = b2f(e0[k][j]);
                    ek[8 + j] = b2f(e1[k][j]);
                }
                float m0 = ebv.x + b2f(gv[k][0]);
                float m1 = ebv.y + b2f(gv[k][1]);
                float m2 = ebv.z + b2f(gv[k][2]);
                float m3 = ebv.w + b2f(gv[k][3]);
#pragma unroll
                for (int kk = 0; kk < 16; ++kk) {
                    m0 = fmaf(ek[kk], ewv[kk][0], m0);
                    m1 = fmaf(ek[kk], ewv[kk][1], m1);
                    m2 = fmaf(ek[kk], ewv[kk][2], m2);
                    m3 = fmaf(ek[kk], ewv[kk][3], m3);
                }
                a0 += fmaxf(m0, 0.f);
                a1 += fmaxf(m1, 0.f);
                a2 += fmaxf(m2, 0.f);
                a3 += fmaxf(m3, 0.f);
            }
        }
        t += m;
    }
#undef AGG_FLUSH
}

// ----------------------------------------------------------- bf16 MFMA GEMM
// C[M,256] = act(A@W + bias). BM=256 (4 waves x 64 rows), BN=64, K=256.
// B panel (64x256 bf16 = 32KB) in LDS (XOR swizzle); depth-1 A prefetch.
// Epilogue: per-wave LDS transpose -> 1KB coalesced global_store_dwordx4.
template <bool RELU, bool STATS>
__global__ __launch_bounds__(256, 3) void gemm_k(const short* __restrict__ A,
                                                 const short* __restrict__ wT,
                                                 const float* __restrict__ bias,
                                                 short* __restrict__ C,
                                                 float* __restrict__ stats, int M) {
    __shared__ short Bs[64 * 256]; // 32KB
    char* BsB = (char*)Bs;
    int wv = threadIdx.x >> 6, lane = threadIdx.x & 63;
    int lr = lane & 15, lg = lane >> 4;
    int c0 = blockIdx.y * 64;
    int bm = blockIdx.x * 256;
    int r0 = bm + wv * 64;

    const char* panel = (const char*)(wT + (size_t)c0 * 256);
    {
        float4 v[4];
#pragma unroll
        for (int it = 0; it < 4; ++it)
            v[it] = *reinterpret_cast<const float4*>(panel + (threadIdx.x + it * 256) * 16);
#pragma unroll
        for (int it = 0; it < 4; ++it) {
            int o = (threadIdx.x + it * 256) * 16;
            int n = o >> 9;
            *reinterpret_cast<float4*>(BsB + (o ^ ((n & 7) << 4))) = v[it];
        }
        float4 v2[4];
#pragma unroll
        for (int it = 4; it < 8; ++it)
            v2[it - 4] = *reinterpret_cast<const float4*>(panel + (threadIdx.x + it * 256) * 16);
#pragma unroll
        for (int it = 4; it < 8; ++it) {
            int o = (threadIdx.x + it * 256) * 16;
            int n = o >> 9;
            *reinterpret_cast<float4*>(BsB + (o ^ ((n & 7) << 4))) = v2[it - 4];
        }
    }

    const short* pA[4];
    bool gok[4];
#pragma unroll
    for (int f = 0; f < 4; ++f) {
        int r = r0 + f * 16 + lr;
        gok[f] = r < M;
        pA[f] = A + (size_t)r * 256 + lg * 8;
    }

    f32x4 acc[4][4] = {};
    bf16x8 aCur[4] = {}, aNxt[4] = {};
#pragma unroll
    for (int f = 0; f < 4; ++f)
        if (gok[f]) aCur[f] = *reinterpret_cast<const bf16x8*>(pA[f]);

    __syncthreads();

    for (int k0 = 0; k0 < 256; k0 += 32) {
        if (k0 < 224) {
#pragma unroll
            for (int f = 0; f < 4; ++f)
                if (gok[f]) aNxt[f] = *reinterpret_cast<const bf16x8*>(pA[f] + k0 + 32);
        }
#pragma unroll
        for (int cc = 0; cc < 4; ++cc) {
            int n = cc * 16 + lr;
            int kb = k0 * 2 + lg * 16;
            bf16x8 b = *reinterpret_cast<const bf16x8*>(
                BsB + ((n * 512 + (kb ^ ((n & 7) << 4)))));
#pragma unroll
            for (int f = 0; f < 4; ++f)
                acc[f][cc] = __builtin_amdgcn_mfma_f32_16x16x32_bf16(aCur[f], b, acc[f][cc], 0, 0, 0);
        }
#pragma unroll
        for (int f = 0; f < 4; ++f) aCur[f] = aNxt[f];
    }

    __syncthreads();
    char* S = BsB + wv * 8192;
#pragma unroll
    for (int cc = 0; cc < 4; ++cc) {
        int colL = cc * 16 + lr;
        float bi = bias[c0 + colL];
        float s = 0.f, ss2 = 0.f;
#pragma unroll
        for (int f = 0; f < 4; ++f)
#pragma unroll
            for (int i = 0; i < 4; ++i) {
                int rowL = f * 16 + lg * 4 + i;
                float v = acc[f][cc][i] + bi;
                if (RELU) v = fmaxf(v, 0.f);
                if (STATS && (r0 + rowL) < M) { s += v; ss2 = fmaf(v, v, ss2); }
                int byte = rowL * 128 + ((colL * 2) ^ ((rowL & 7) << 4));
                *reinterpret_cast<short*>(S + byte) = f2b(v);
            }
        if (STATS) {
            s   += __shfl_xor(s, 16);  ss2 += __shfl_xor(ss2, 16);
            s   += __shfl_xor(s, 32);  ss2 += __shfl_xor(ss2, 32);
            if (lg == 0) {
                atomicAdd(&stats[c0 + colL], s);
                atomicAdd(&stats[HID + c0 + colL], ss2);
            }
        }
    }
    asm volatile("s_waitcnt lgkmcnt(0)" ::: "memory");
#pragma unroll
    for (int j = 0; j < 8; ++j) {
        int rowL = j * 8 + (lane >> 3);
        int cb = (lane & 7) * 16;
        int byte = rowL * 128 + (cb ^ ((rowL & 7) << 4));
        int4 d = *reinterpret_cast<const int4*>(S + byte);
        int grow = r0 + rowL;
        if (grow < M)
            *reinterpret_cast<int4*>((char*)C + (size_t)grow * 512 + c0 * 2 + cb) = d;
    }
}

// ------------------------------------------------------- BN normalize+relu
__global__ void bn_relu_k(const short* __restrict__ z, short* __restrict__ hb,
                          const float* __restrict__ stats,
                          const float* __restrict__ gamma,
                          const float* __restrict__ beta) {
    int gidx = blockIdx.x * 256 + threadIdx.x;
    int base = gidx * 4;
    int j = base & 255;
    u16x4 z4 = *reinterpret_cast<const u16x4*>(z + base);
    u16x4 o;
#pragma unroll
    for (int i = 0; i < 4; ++i) {
        float mu  = stats[j + i] * (1.f / NNODES);
        float var = stats[HID + j + i] * (1.f / NNODES) - mu * mu;
        float inv = rsqrtf(var + 1e-5f);
        float v = (b2f(z4[i]) - mu) * inv * gamma[j + i] + beta[j + i];
        o[i] = (unsigned short)f2b(fmaxf(v, 0.f));
    }
    *reinterpret_cast<u16x4*>(hb + base) = o;
}

// ------------------------------------------------------------------ pool
#define PNB 64
__global__ void pool_k(const short* __restrict__ hb, const int* __restrict__ batch,
                       float* __restrict__ g) {
    int j = threadIdx.x;
    int n0 = blockIdx.x * PNB;
    int n1 = min(n0 + PNB, NNODES);
    int cur = batch[n0];
    float acc = 0.f;
    for (int n = n0; n < n1; ++n) {
        int b = batch[n];
        if (b != cur) {
            atomicAdd(&g[(size_t)cur * HID + j], acc);
            acc = 0.f; cur = b;
        }
        acc += b2f((unsigned short)hb[(size_t)n * HID + j]);
    }
    atomicAdd(&g[(size_t)cur * HID + j], acc);
}

// ------------------------------------------------------------------ head
__global__ void head_k(const float* __restrict__ g, const float* __restrict__ w1,
                       const float* __restrict__ b1, const float* __restrict__ w2,
                       const float* __restrict__ b2, float* __restrict__ out) {
    int gi = blockIdx.x;
    int j  = threadIdx.x;
    __shared__ float gr[256];
    __shared__ float hid[128];
    gr[j]       = g[gi * 256 + j];
    gr[j + 128] = g[gi * 256 + 128 + j];
    __syncthreads();
    float acc = b1[j];
    for (int k = 0; k < 256; ++k) acc = fmaf(gr[k], w1[k * 128 + j], acc);
    hid[j] = fmaxf(acc, 0.f);
    __syncthreads();
    if (j < 12) {
        float o = b2[j];
#pragma unroll
        for (int k = 0; k < 128; ++k) o = fmaf(hid[k], w2[k * 12 + j], o);
        out[gi * 12 + j] = o;
    }
}

// ---------------------------------------------------------------- launch
extern "C" void kernel_launch(void* const* d_in, const int* in_sizes, int n_in,
                              void* d_out, int out_size, void* d_ws, size_t ws_size,
                              hipStream_t stream) {
    const float* x     = (const float*)d_in[0];
    const int*   ei    = (const int*)d_in[1];
    const int*   batch = (const int*)d_in[2];
    const float* eattr = (const float*)d_in[3];
    const float* nw    = (const float*)d_in[4];
    const float* nb    = (const float*)d_in[5];
    const float* ew    = (const float*)d_in[6];
    const float* eb    = (const float*)d_in[7];
    const float* w1    = (const float*)d_in[8];
    const float* b1    = (const float*)d_in[9];
    const float* w2    = (const float*)d_in[10];
    const float* b2    = (const float*)d_in[11];
    const float* gam   = (const float*)d_in[12];
    const float* bet   = (const float*)d_in[13];
    const float* hw1   = (const float*)d_in[14];
    const float* hb1   = (const float*)d_in[15];
    const float* hw2   = (const float*)d_in[16];
    const float* hb2   = (const float*)d_in[17];
    float* out = (float*)d_out;

    const size_t NH = (size_t)NNODES * HID;
    size_t off = 0;
    char* base = (char*)d_ws;
    auto alloc = [&](size_t bytes) -> void* {
        void* p = base + off;
        off += (bytes + 255) & ~(size_t)255;
        return p;
    };
    short* hb       = (short*)alloc(NH * 2);
    short* zb       = (short*)alloc(NH * 2);
    short* z1b      = (short*)alloc(NH * 2);
    short* wT       = (short*)alloc(8 * 65536 * 2);
    short* eattr_bs = (short*)alloc((size_t)NEDGES * 16 * 2);  // 9.6 MB
    int*   srcs     = (int*)alloc((size_t)NEDGES * 4);
    float* stats    = (float*)alloc(512 * 4);
    float* g        = (float*)alloc((size_t)NGRAPHS * HID * 4);
    int*   deg      = (int*)alloc((size_t)NNODES * 4);
    int*   partial  = (int*)alloc((size_t)NNODES * 4);
    int*   btot     = (int*)alloc(256 * 4);
    int*   row_ptr  = (int*)alloc((size_t)(NNODES + 1) * 4);
    int*   cursor   = (int*)alloc((size_t)NNODES * 4);
    int*   eid      = (int*)alloc((size_t)NEDGES * 4);

    wconv_k<<<dim3(256, 4), 256, 0, stream>>>(w1, wT);
    wconv_k<<<dim3(256, 4), 256, 0, stream>>>(w2, wT + 4 * 65536);
    node_embed_k<<<NNODES, 256, 0, stream>>>(x, nw, nb, hb);

    hipMemsetAsync(deg, 0, (size_t)NNODES * 4, stream);
    deg_k<<<(NEDGES + 255) / 256, 256, 0, stream>>>(ei, deg);
    const int NB = (NNODES + 255) / 256;
    scan1_k<<<NB, 256, 0, stream>>>(deg, partial, btot);
    scan2_k<<<1, 256, 0, stream>>>(btot, NB);
    scan3_k<<<NB, 256, 0, stream>>>(deg, partial, btot, row_ptr, cursor);
    fill_k<<<(NEDGES + 255) / 256, 256, 0, stream>>>(ei, cursor, eid);
    esort2_k<<<(NEDGES + 255) / 256, 256, 0, stream>>>(eattr, ei, eid, eattr_bs, srcs);

    dim3 ggrid((NNODES + 255) / 256, 4);
    for (int l = 0; l < L; ++l) {
        agg_k<<<NNODES / (4 * AGG_NPW), 256, 0, stream>>>(
            hb, eattr_bs, srcs, row_ptr, ew, eb, zb, stats);
        gemm_k<true, false><<<ggrid, 256, 0, stream>>>(
            zb, wT + (size_t)l * 65536, b1 + l * HID, z1b, nullptr, NNODES);
        gemm_k<false, true><<<ggrid, 256, 0, stream>>>(
            z1b, wT + (size_t)(4 + l) * 65536, b2 + l * HID, zb, stats, NNODES);
        bn_relu_k<<<(int)(NH / 1024), 256, 0, stream>>>(
            zb, hb, stats, gam + l * HID, bet + l * HID);
    }

    hipMemsetAsync(g, 0, (size_t)NGRAPHS * HID * 4, stream);
    pool_k<<<(NNODES + PNB - 1) / PNB, 256, 0, stream>>>(hb, batch, g);
    head_k<<<NGRAPHS, 128, 0, stream>>>(g, hw1, hb1, hw2, hb2, out);
}

// Round 8
// 843.238 us; speedup vs baseline: 1.1119x; 1.1119x over previous
//
#include <hip/hip_runtime.h>
#include <hip/hip_bf16.h>

#define HID     256
#define NNODES  50000
#define NEDGES  300000
#define NGRAPHS 128
#define L       4

typedef __attribute__((ext_vector_type(8))) short bf16x8;
typedef __attribute__((ext_vector_type(4))) float f32x4;
typedef __attribute__((ext_vector_type(4))) unsigned short u16x4;

static __device__ __forceinline__ float b2f(unsigned short s) {
    union { unsigned u; float f; } v;
    v.u = ((unsigned)s) << 16;
    return v.f;
}
static __device__ __forceinline__ short f2b(float f) {
    __hip_bfloat16 h = __float2bfloat16(f);
    return *reinterpret_cast<short*>(&h);
}

// ------------------------------------------------ weight convert + transpose
__global__ void wconv_k(const float* __restrict__ w, short* __restrict__ wT) {
    int m = blockIdx.y, n = blockIdx.x, k = threadIdx.x;
    wT[(size_t)m * 65536 + n * 256 + k] = f2b(w[(size_t)m * 65536 + k * 256 + n]);
}

// ---------------------------------------------------------------- node embed
__global__ void node_embed_k(const float* __restrict__ x,
                             const float* __restrict__ w,
                             const float* __restrict__ b,
                             short* __restrict__ hb) {
    int n = blockIdx.x;
    int j = threadIdx.x;
    __shared__ float xr[32];
    if (j < 32) xr[j] = x[n * 32 + j];
    __syncthreads();
    float acc = b[j];
#pragma unroll
    for (int k = 0; k < 32; ++k) acc = fmaf(xr[k], w[k * HID + j], acc);
    hb[(size_t)n * HID + j] = f2b(acc);
}

// ------------------------------------------------------------- CSR building
__global__ void deg_k(const int* __restrict__ ei, int* __restrict__ deg) {
    int e = blockIdx.x * 256 + threadIdx.x;
    if (e < NEDGES) atomicAdd(&deg[ei[NEDGES + e]], 1);
}

__global__ void scan1_k(const int* __restrict__ deg, int* __restrict__ partial,
                        int* __restrict__ btot) {
    __shared__ int s[256];
    int t = threadIdx.x;
    int gi = blockIdx.x * 256 + t;
    s[t] = (gi < NNODES) ? deg[gi] : 0;
    __syncthreads();
    for (int off = 1; off < 256; off <<= 1) {
        int u = (t >= off) ? s[t - off] : 0;
        __syncthreads();
        s[t] += u;
        __syncthreads();
    }
    if (gi < NNODES) partial[gi] = s[t];
    if (t == 255) btot[blockIdx.x] = s[255];
}

__global__ void scan2_k(int* __restrict__ btot, int nb) {
    __shared__ int s[256];
    int t = threadIdx.x;
    s[t] = (t < nb) ? btot[t] : 0;
    __syncthreads();
    for (int off = 1; off < 256; off <<= 1) {
        int u = (t >= off) ? s[t - off] : 0;
        __syncthreads();
        s[t] += u;
        __syncthreads();
    }
    btot[t] = s[t];
}

__global__ void scan3_k(const int* __restrict__ deg, const int* __restrict__ partial,
                        const int* __restrict__ btot, int* __restrict__ row_ptr,
                        int* __restrict__ cursor) {
    int gi = blockIdx.x * 256 + threadIdx.x;
    if (gi >= NNODES) return;
    int b = blockIdx.x;
    int incl = partial[gi] + (b ? btot[b - 1] : 0);
    int start = incl - deg[gi];
    row_ptr[gi] = start;
    cursor[gi] = start;
    if (gi == NNODES - 1) row_ptr[NNODES] = incl;
}

// fill: slot[e] = CSR position of edge e; srcs[pos] = src node (scatter).
__global__ void fill_k(const int* __restrict__ ei, int* __restrict__ cursor,
                       int* __restrict__ slot, int* __restrict__ srcs) {
    int e = blockIdx.x * 256 + threadIdx.x;
    if (e < NEDGES) {
        int d = ei[NEDGES + e];
        int pos = atomicAdd(&cursor[d], 1);
        slot[e] = pos;
        srcs[pos] = ei[e];
    }
}

// ---------------- one-time: ea_s[slot[e]] = bf16(eattr[e] @ ew + eb)
// eattr read STREAMING (coalesced); only the 512B row-write scatters.
// 4 edges per wave, all loads independent & in flight.
__global__ __launch_bounds__(256) void ea_k(const float* __restrict__ eattr,
                                            const int* __restrict__ slot,
                                            const float* __restrict__ ew,
                                            const float* __restrict__ ebias,
                                            short* __restrict__ ea_s) {
    int lane = threadIdx.x & 63, wv = threadIdx.x >> 6;
    int c = lane * 4;
    float ewv[16][4];
#pragma unroll
    for (int k = 0; k < 16; ++k) {
        float4 v = *reinterpret_cast<const float4*>(ew + k * 256 + c);
        ewv[k][0] = v.x; ewv[k][1] = v.y; ewv[k][2] = v.z; ewv[k][3] = v.w;
    }
    float4 ebv = *reinterpret_cast<const float4*>(ebias + c);

    int t0 = (blockIdx.x * 4 + wv) * 4;
    if (t0 >= NEDGES) return;
    int4 sl = *reinterpret_cast<const int4*>(slot + t0);
    int sv[4] = { sl.x, sl.y, sl.z, sl.w };
    float4 q[4][4];
#pragma unroll
    for (int j = 0; j < 4; ++j) {
        const float4* ep = reinterpret_cast<const float4*>(eattr + (size_t)(t0 + j) * 16);
        q[j][0] = ep[0]; q[j][1] = ep[1]; q[j][2] = ep[2]; q[j][3] = ep[3];
    }
#pragma unroll
    for (int j = 0; j < 4; ++j) {
        float m[4] = { ebv.x, ebv.y, ebv.z, ebv.w };
        float ek[16] = { q[j][0].x, q[j][0].y, q[j][0].z, q[j][0].w,
                         q[j][1].x, q[j][1].y, q[j][1].z, q[j][1].w,
                         q[j][2].x, q[j][2].y, q[j][2].z, q[j][2].w,
                         q[j][3].x, q[j][3].y, q[j][3].z, q[j][3].w };
#pragma unroll
        for (int k = 0; k < 16; ++k)
#pragma unroll
            for (int i = 0; i < 4; ++i) m[i] = fmaf(ek[k], ewv[k][i], m[i]);
        u16x4 o;
#pragma unroll
        for (int i = 0; i < 4; ++i) o[i] = (unsigned short)f2b(m[i]);
        *reinterpret_cast<u16x4*>(ea_s + (size_t)sv[j] * HID + c) = o;
    }
}

// ------------------------------------------------- CSR aggregate, wave-per-node
// zb[n] = hb[n] + sum_t relu(hb[srcs[t]] + ea_s[t]); one wave per node,
// window of 8 edges (16 loads in flight). Block 0 zeroes BN stats.
__global__ __launch_bounds__(256) void agg_k(
    const short* __restrict__ hb, const short* __restrict__ ea_s,
    const int* __restrict__ srcs, const int* __restrict__ row_ptr,
    short* __restrict__ zb, float* __restrict__ stats) {
    if (blockIdx.x == 0) {
        stats[threadIdx.x] = 0.f;
        stats[threadIdx.x + 256] = 0.f;
    }
    int lane = threadIdx.x & 63, wv = threadIdx.x >> 6;
    int c = lane * 4;
    int n = blockIdx.x * 4 + wv;          // grid exact: 12500*4 = 50000
    int beg = row_ptr[n], end = row_ptr[n + 1];
    u16x4 h4 = *reinterpret_cast<const u16x4*>(hb + (size_t)n * HID + c);
    float a0 = b2f(h4[0]), a1 = b2f(h4[1]), a2 = b2f(h4[2]), a3 = b2f(h4[3]);

    for (int t = beg; t < end; t += 8) {
        int m = min(8, end - t);
        int ss[8];
        u16x4 ev[8], gv[8];
#pragma unroll
        for (int k = 0; k < 8; ++k)
            if (k < m) ss[k] = srcs[t + k];
#pragma unroll
        for (int k = 0; k < 8; ++k)
            if (k < m) {
                ev[k] = *reinterpret_cast<const u16x4*>(ea_s + (size_t)(t + k) * HID + c);
                gv[k] = *reinterpret_cast<const u16x4*>(hb + (size_t)ss[k] * HID + c);
            }
#pragma unroll
        for (int k = 0; k < 8; ++k)
            if (k < m) {
                a0 += fmaxf(b2f(ev[k][0]) + b2f(gv[k][0]), 0.f);
                a1 += fmaxf(b2f(ev[k][1]) + b2f(gv[k][1]), 0.f);
                a2 += fmaxf(b2f(ev[k][2]) + b2f(gv[k][2]), 0.f);
                a3 += fmaxf(b2f(ev[k][3]) + b2f(gv[k][3]), 0.f);
            }
    }
    u16x4 o;
    o[0] = (unsigned short)f2b(a0);
    o[1] = (unsigned short)f2b(a1);
    o[2] = (unsigned short)f2b(a2);
    o[3] = (unsigned short)f2b(a3);
    *reinterpret_cast<u16x4*>(zb + (size_t)n * HID + c) = o;
}

// ----------------------------------------------------------- bf16 MFMA GEMM
// C[M,256] = act(A@W + bias). BM=256 (4 waves x 64 rows), BN=64, K=256.
// Linear grid + XCD-chunked swizzle: the 4 n-tiles of one A-panel run on
// the SAME XCD -> A-panel served from that XCD's L2 (A fetched once).
// B panel (64x256 bf16 = 32KB) in LDS (XOR swizzle); depth-1 A prefetch.
// Epilogue: per-wave LDS transpose -> 1KB coalesced global_store_dwordx4.
template <bool RELU, bool STATS>
__global__ __launch_bounds__(256, 3) void gemm_k(const short* __restrict__ A,
                                                 const short* __restrict__ wT,
                                                 const float* __restrict__ bias,
                                                 short* __restrict__ C,
                                                 float* __restrict__ stats, int M) {
    __shared__ short Bs[64 * 256]; // 32KB
    char* BsB = (char*)Bs;
    int wv = threadIdx.x >> 6, lane = threadIdx.x & 63;
    int lr = lane & 15, lg = lane >> 4;

    // XCD-chunked swizzle (grid 784 = 8 * 98)
    int bid = blockIdx.x;
    int sw = (bid & 7) * (gridDim.x >> 3) + (bid >> 3);
    int c0 = (sw & 3) * 64;
    int r0 = (sw >> 2) * 256 + wv * 64;

    const char* panel = (const char*)(wT + (size_t)c0 * 256);
    {
        float4 v[4];
#pragma unroll
        for (int it = 0; it < 4; ++it)
            v[it] = *reinterpret_cast<const float4*>(panel + (threadIdx.x + it * 256) * 16);
#pragma unroll
        for (int it = 0; it < 4; ++it) {
            int o = (threadIdx.x + it * 256) * 16;
            int n = o >> 9;
            *reinterpret_cast<float4*>(BsB + (o ^ ((n & 7) << 4))) = v[it];
        }
        float4 v2[4];
#pragma unroll
        for (int it = 4; it < 8; ++it)
            v2[it - 4] = *reinterpret_cast<const float4*>(panel + (threadIdx.x + it * 256) * 16);
#pragma unroll
        for (int it = 4; it < 8; ++it) {
            int o = (threadIdx.x + it * 256) * 16;
            int n = o >> 9;
            *reinterpret_cast<float4*>(BsB + (o ^ ((n & 7) << 4))) = v2[it - 4];
        }
    }

    const short* pA[4];
    bool gok[4];
#pragma unroll
    for (int f = 0; f < 4; ++f) {
        int r = r0 + f * 16 + lr;
        gok[f] = r < M;
        pA[f] = A + (size_t)r * 256 + lg * 8;
    }

    f32x4 acc[4][4] = {};
    bf16x8 aCur[4] = {}, aNxt[4] = {};
#pragma unroll
    for (int f = 0; f < 4; ++f)
        if (gok[f]) aCur[f] = *reinterpret_cast<const bf16x8*>(pA[f]);

    __syncthreads();

    for (int k0 = 0; k0 < 256; k0 += 32) {
        if (k0 < 224) {
#pragma unroll
            for (int f = 0; f < 4; ++f)
                if (gok[f]) aNxt[f] = *reinterpret_cast<const bf16x8*>(pA[f] + k0 + 32);
        }
#pragma unroll
        for (int cc = 0; cc < 4; ++cc) {
            int n = cc * 16 + lr;
            int kb = k0 * 2 + lg * 16;
            bf16x8 b = *reinterpret_cast<const bf16x8*>(
                BsB + ((n * 512 + (kb ^ ((n & 7) << 4)))));
#pragma unroll
            for (int f = 0; f < 4; ++f)
                acc[f][cc] = __builtin_amdgcn_mfma_f32_16x16x32_bf16(aCur[f], b, acc[f][cc], 0, 0, 0);
        }
#pragma unroll
        for (int f = 0; f < 4; ++f) aCur[f] = aNxt[f];
    }

    __syncthreads();
    char* S = BsB + wv * 8192;
#pragma unroll
    for (int cc = 0; cc < 4; ++cc) {
        int colL = cc * 16 + lr;
        float bi = bias[c0 + colL];
        float s = 0.f, ss2 = 0.f;
#pragma unroll
        for (int f = 0; f < 4; ++f)
#pragma unroll
            for (int i = 0; i < 4; ++i) {
                int rowL = f * 16 + lg * 4 + i;
                float v = acc[f][cc][i] + bi;
                if (RELU) v = fmaxf(v, 0.f);
                if (STATS && (r0 + rowL) < M) { s += v; ss2 = fmaf(v, v, ss2); }
                int byte = rowL * 128 + ((colL * 2) ^ ((rowL & 7) << 4));
                *reinterpret_cast<short*>(S + byte) = f2b(v);
            }
        if (STATS) {
            s   += __shfl_xor(s, 16);  ss2 += __shfl_xor(ss2, 16);
            s   += __shfl_xor(s, 32);  ss2 += __shfl_xor(ss2, 32);
            if (lg == 0) {
                atomicAdd(&stats[c0 + colL], s);
                atomicAdd(&stats[HID + c0 + colL], ss2);
            }
        }
    }
    asm volatile("s_waitcnt lgkmcnt(0)" ::: "memory");
#pragma unroll
    for (int j = 0; j < 8; ++j) {
        int rowL = j * 8 + (lane >> 3);
        int cb = (lane & 7) * 16;
        int byte = rowL * 128 + (cb ^ ((rowL & 7) << 4));
        int4 d = *reinterpret_cast<const int4*>(S + byte);
        int grow = r0 + rowL;
        if (grow < M)
            *reinterpret_cast<int4*>((char*)C + (size_t)grow * 512 + c0 * 2 + cb) = d;
    }
}

// ------------------------------------------------------- BN normalize+relu
__global__ void bn_relu_k(const short* __restrict__ z, short* __restrict__ hb,
                          const float* __restrict__ stats,
                          const float* __restrict__ gamma,
                          const float* __restrict__ beta) {
    int gidx = blockIdx.x * 256 + threadIdx.x;
    int base = gidx * 4;
    int j = base & 255;
    u16x4 z4 = *reinterpret_cast<const u16x4*>(z + base);
    u16x4 o;
#pragma unroll
    for (int i = 0; i < 4; ++i) {
        float mu  = stats[j + i] * (1.f / NNODES);
        float var = stats[HID + j + i] * (1.f / NNODES) - mu * mu;
        float inv = rsqrtf(var + 1e-5f);
        float v = (b2f(z4[i]) - mu) * inv * gamma[j + i] + beta[j + i];
        o[i] = (unsigned short)f2b(fmaxf(v, 0.f));
    }
    *reinterpret_cast<u16x4*>(hb + base) = o;
}

// ------------------------------------------------------------------ pool
#define PNB 64
__global__ void pool_k(const short* __restrict__ hb, const int* __restrict__ batch,
                       float* __restrict__ g) {
    int j = threadIdx.x;
    int n0 = blockIdx.x * PNB;
    int n1 = min(n0 + PNB, NNODES);
    int cur = batch[n0];
    float acc = 0.f;
    for (int n = n0; n < n1; ++n) {
        int b = batch[n];
        if (b != cur) {
            atomicAdd(&g[(size_t)cur * HID + j], acc);
            acc = 0.f; cur = b;
        }
        acc += b2f((unsigned short)hb[(size_t)n * HID + j]);
    }
    atomicAdd(&g[(size_t)cur * HID + j], acc);
}

// ------------------------------------------------------------------ head
__global__ void head_k(const float* __restrict__ g, const float* __restrict__ w1,
                       const float* __restrict__ b1, const float* __restrict__ w2,
                       const float* __restrict__ b2, float* __restrict__ out) {
    int gi = blockIdx.x;
    int j  = threadIdx.x;
    __shared__ float gr[256];
    __shared__ float hid[128];
    gr[j]       = g[gi * 256 + j];
    gr[j + 128] = g[gi * 256 + 128 + j];
    __syncthreads();
    float acc = b1[j];
    for (int k = 0; k < 256; ++k) acc = fmaf(gr[k], w1[k * 128 + j], acc);
    hid[j] = fmaxf(acc, 0.f);
    __syncthreads();
    if (j < 12) {
        float o = b2[j];
#pragma unroll
        for (int k = 0; k < 128; ++k) o = fmaf(hid[k], w2[k * 12 + j], o);
        out[gi * 12 + j] = o;
    }
}

// ---------------------------------------------------------------- launch
extern "C" void kernel_launch(void* const* d_in, const int* in_sizes, int n_in,
                              void* d_out, int out_size, void* d_ws, size_t ws_size,
                              hipStream_t stream) {
    const float* x     = (const float*)d_in[0];
    const int*   ei    = (const int*)d_in[1];
    const int*   batch = (const int*)d_in[2];
    const float* eattr = (const float*)d_in[3];
    const float* nw    = (const float*)d_in[4];
    const float* nb    = (const float*)d_in[5];
    const float* ew    = (const float*)d_in[6];
    const float* eb    = (const float*)d_in[7];
    const float* w1    = (const float*)d_in[8];
    const float* b1    = (const float*)d_in[9];
    const float* w2    = (const float*)d_in[10];
    const float* b2    = (const float*)d_in[11];
    const float* gam   = (const float*)d_in[12];
    const float* bet   = (const float*)d_in[13];
    const float* hw1   = (const float*)d_in[14];
    const float* hb1   = (const float*)d_in[15];
    const float* hw2   = (const float*)d_in[16];
    const float* hb2   = (const float*)d_in[17];
    float* out = (float*)d_out;

    const size_t NH = (size_t)NNODES * HID;
    const size_t EH = (size_t)NEDGES * HID;
    size_t off = 0;
    char* base = (char*)d_ws;
    auto alloc = [&](size_t bytes) -> void* {
        void* p = base + off;
        off += (bytes + 255) & ~(size_t)255;
        return p;
    };
    short* hb      = (short*)alloc(NH * 2);
    short* zb      = (short*)alloc(NH * 2);
    short* z1b     = (short*)alloc(NH * 2);
    short* wT      = (short*)alloc(8 * 65536 * 2);
    short* ea_s    = (short*)alloc(EH * 2);       // 153.6 MB, layer-invariant
    int*   srcs    = (int*)alloc((size_t)NEDGES * 4);
    float* stats   = (float*)alloc(512 * 4);
    float* g       = (float*)alloc((size_t)NGRAPHS * HID * 4);
    int*   deg     = (int*)alloc((size_t)NNODES * 4);
    int*   partial = (int*)alloc((size_t)NNODES * 4);
    int*   btot    = (int*)alloc(256 * 4);
    int*   row_ptr = (int*)alloc((size_t)(NNODES + 1) * 4);
    int*   cursor  = (int*)alloc((size_t)NNODES * 4);
    int*   slot    = (int*)alloc((size_t)NEDGES * 4);

    wconv_k<<<dim3(256, 4), 256, 0, stream>>>(w1, wT);
    wconv_k<<<dim3(256, 4), 256, 0, stream>>>(w2, wT + 4 * 65536);
    node_embed_k<<<NNODES, 256, 0, stream>>>(x, nw, nb, hb);

    hipMemsetAsync(deg, 0, (size_t)NNODES * 4, stream);
    deg_k<<<(NEDGES + 255) / 256, 256, 0, stream>>>(ei, deg);
    const int NB = (NNODES + 255) / 256;
    scan1_k<<<NB, 256, 0, stream>>>(deg, partial, btot);
    scan2_k<<<1, 256, 0, stream>>>(btot, NB);
    scan3_k<<<NB, 256, 0, stream>>>(deg, partial, btot, row_ptr, cursor);
    fill_k<<<(NEDGES + 255) / 256, 256, 0, stream>>>(ei, cursor, slot, srcs);
    ea_k<<<NEDGES / 16, 256, 0, stream>>>(eattr, slot, ew, eb, ea_s);

    const int GG = ((NNODES + 255) / 256) * 4;   // 784, %8==0
    for (int l = 0; l < L; ++l) {
        agg_k<<<NNODES / 4, 256, 0, stream>>>(
            hb, ea_s, srcs, row_ptr, zb, stats);
        gemm_k<true, false><<<GG, 256, 0, stream>>>(
            zb, wT + (size_t)l * 65536, b1 + l * HID, z1b, nullptr, NNODES);
        gemm_k<false, true><<<GG, 256, 0, stream>>>(
            z1b, wT + (size_t)(4 + l) * 65536, b2 + l * HID, zb, stats, NNODES);
        bn_relu_k<<<(int)(NH / 1024), 256, 0, stream>>>(
            zb, hb, stats, gam + l * HID, bet + l * HID);
    }

    hipMemsetAsync(g, 0, (size_t)NGRAPHS * HID * 4, stream);
    pool_k<<<(NNODES + PNB - 1) / PNB, 256, 0, stream>>>(hb, batch, g);
    head_k<<<NGRAPHS, 128, 0, stream>>>(g, hw1, hb1, hw2, hb2, out);
}

// Round 10
// 835.638 us; speedup vs baseline: 1.1220x; 1.0091x over previous
//
#include <hip/hip_runtime.h>
#include <hip/hip_bf16.h>

#define HID     256
#define NNODES  50000
#define NEDGES  300000
#define NGRAPHS 128
#define L       4

typedef __attribute__((ext_vector_type(8))) short bf16x8;
typedef __attribute__((ext_vector_type(4))) float f32x4;
typedef __attribute__((ext_vector_type(4))) unsigned short u16x4;

static __device__ __forceinline__ float b2f(unsigned short s) {
    union { unsigned u; float f; } v;
    v.u = ((unsigned)s) << 16;
    return v.f;
}
static __device__ __forceinline__ short f2b(float f) {
    __hip_bfloat16 h = __float2bfloat16(f);
    return *reinterpret_cast<short*>(&h);
}

// ------------------------------------------------ weight convert + transpose
__global__ void wconv_k(const float* __restrict__ w, short* __restrict__ wT) {
    int m = blockIdx.y, n = blockIdx.x, k = threadIdx.x;
    wT[(size_t)m * 65536 + n * 256 + k] = f2b(w[(size_t)m * 65536 + k * 256 + n]);
}

// ---------------------------------------------------------------- node embed
__global__ void node_embed_k(const float* __restrict__ x,
                             const float* __restrict__ w,
                             const float* __restrict__ b,
                             short* __restrict__ hb) {
    int n = blockIdx.x;
    int j = threadIdx.x;
    __shared__ float xr[32];
    if (j < 32) xr[j] = x[n * 32 + j];
    __syncthreads();
    float acc = b[j];
#pragma unroll
    for (int k = 0; k < 32; ++k) acc = fmaf(xr[k], w[k * HID + j], acc);
    hb[(size_t)n * HID + j] = f2b(acc);
}

// ------------------------------------------------------------- CSR building
__global__ void deg_k(const int* __restrict__ ei, int* __restrict__ deg) {
    int e = blockIdx.x * 256 + threadIdx.x;
    if (e < NEDGES) atomicAdd(&deg[ei[NEDGES + e]], 1);
}

__global__ void scan1_k(const int* __restrict__ deg, int* __restrict__ partial,
                        int* __restrict__ btot) {
    __shared__ int s[256];
    int t = threadIdx.x;
    int gi = blockIdx.x * 256 + t;
    s[t] = (gi < NNODES) ? deg[gi] : 0;
    __syncthreads();
    for (int off = 1; off < 256; off <<= 1) {
        int u = (t >= off) ? s[t - off] : 0;
        __syncthreads();
        s[t] += u;
        __syncthreads();
    }
    if (gi < NNODES) partial[gi] = s[t];
    if (t == 255) btot[blockIdx.x] = s[255];
}

__global__ void scan2_k(int* __restrict__ btot, int nb) {
    __shared__ int s[256];
    int t = threadIdx.x;
    s[t] = (t < nb) ? btot[t] : 0;
    __syncthreads();
    for (int off = 1; off < 256; off <<= 1) {
        int u = (t >= off) ? s[t - off] : 0;
        __syncthreads();
        s[t] += u;
        __syncthreads();
    }
    btot[t] = s[t];
}

__global__ void scan3_k(const int* __restrict__ deg, const int* __restrict__ partial,
                        const int* __restrict__ btot, int* __restrict__ row_ptr,
                        int* __restrict__ cursor) {
    int gi = blockIdx.x * 256 + threadIdx.x;
    if (gi >= NNODES) return;
    int b = blockIdx.x;
    int incl = partial[gi] + (b ? btot[b - 1] : 0);
    int start = incl - deg[gi];
    row_ptr[gi] = start;
    cursor[gi] = start;
    if (gi == NNODES - 1) row_ptr[NNODES] = incl;
}

// fill: slot[e] = CSR position of edge e; srcs[pos] = src node (scatter).
__global__ void fill_k(const int* __restrict__ ei, int* __restrict__ cursor,
                       int* __restrict__ slot, int* __restrict__ srcs) {
    int e = blockIdx.x * 256 + threadIdx.x;
    if (e < NEDGES) {
        int d = ei[NEDGES + e];
        int pos = atomicAdd(&cursor[d], 1);
        slot[e] = pos;
        srcs[pos] = ei[e];
    }
}

// ---------- scatter the SMALL payload: eattr_s[slot[e]] = eattr[e] (fp32 64B)
__global__ void esort3_k(const float* __restrict__ eattr, const int* __restrict__ slot,
                         float* __restrict__ eattr_s) {
    int e = blockIdx.x * 64 + (threadIdx.x >> 2);   // 64 edges per block
    int q = threadIdx.x & 3;                        // 4 lanes per edge (16B each)
    if (e < NEDGES) {
        float4 v = reinterpret_cast<const float4*>(eattr + (size_t)e * 16)[q];
        reinterpret_cast<float4*>(eattr_s + (size_t)slot[e] * 16)[q] = v;
    }
}

// ---------------- one-time: ea_s[t] = bf16(eattr_s[t] @ ew + eb)
// BOTH sides streaming/coalesced (read slot-ordered eattr, write slot-ordered
// ea). 4 edges per wave -> each wave writes 2KB contiguous.
__global__ __launch_bounds__(256) void ea_k(const float* __restrict__ eattr_s,
                                            const float* __restrict__ ew,
                                            const float* __restrict__ ebias,
                                            short* __restrict__ ea_s) {
    int lane = threadIdx.x & 63, wv = threadIdx.x >> 6;
    int c = lane * 4;
    float ewv[16][4];
#pragma unroll
    for (int k = 0; k < 16; ++k) {
        float4 v = *reinterpret_cast<const float4*>(ew + k * 256 + c);
        ewv[k][0] = v.x; ewv[k][1] = v.y; ewv[k][2] = v.z; ewv[k][3] = v.w;
    }
    float4 ebv = *reinterpret_cast<const float4*>(ebias + c);

    int t0 = (blockIdx.x * 4 + wv) * 4;
    if (t0 >= NEDGES) return;
    float4 q[4][4];
#pragma unroll
    for (int j = 0; j < 4; ++j) {
        const float4* ep = reinterpret_cast<const float4*>(eattr_s + (size_t)(t0 + j) * 16);
        q[j][0] = ep[0]; q[j][1] = ep[1]; q[j][2] = ep[2]; q[j][3] = ep[3];
    }
#pragma unroll
    for (int j = 0; j < 4; ++j) {
        float m[4] = { ebv.x, ebv.y, ebv.z, ebv.w };
        float ek[16] = { q[j][0].x, q[j][0].y, q[j][0].z, q[j][0].w,
                         q[j][1].x, q[j][1].y, q[j][1].z, q[j][1].w,
                         q[j][2].x, q[j][2].y, q[j][2].z, q[j][2].w,
                         q[j][3].x, q[j][3].y, q[j][3].z, q[j][3].w };
#pragma unroll
        for (int k = 0; k < 16; ++k)
#pragma unroll
            for (int i = 0; i < 4; ++i) m[i] = fmaf(ek[k], ewv[k][i], m[i]);
        u16x4 o;
#pragma unroll
        for (int i = 0; i < 4; ++i) o[i] = (unsigned short)f2b(m[i]);
        *reinterpret_cast<u16x4*>(ea_s + (size_t)(t0 + j) * HID + c) = o;
    }
}

// ------------------------------------------------- CSR aggregate, wave-per-node
// zb[n] = hb[n] + sum_t relu(hb[srcs[t]] + ea_s[t]); one wave per node,
// window of 8 edges (16 loads in flight). Block 0 zeroes BN stats.
__global__ __launch_bounds__(256) void agg_k(
    const short* __restrict__ hb, const short* __restrict__ ea_s,
    const int* __restrict__ srcs, const int* __restrict__ row_ptr,
    short* __restrict__ zb, float* __restrict__ stats) {
    if (blockIdx.x == 0) {
        stats[threadIdx.x] = 0.f;
        stats[threadIdx.x + 256] = 0.f;
    }
    int lane = threadIdx.x & 63, wv = threadIdx.x >> 6;
    int c = lane * 4;
    int n = blockIdx.x * 4 + wv;          // grid exact: 12500*4 = 50000
    int beg = row_ptr[n], end = row_ptr[n + 1];
    u16x4 h4 = *reinterpret_cast<const u16x4*>(hb + (size_t)n * HID + c);
    float a0 = b2f(h4[0]), a1 = b2f(h4[1]), a2 = b2f(h4[2]), a3 = b2f(h4[3]);

    for (int t = beg; t < end; t += 8) {
        int m = min(8, end - t);
        int ss[8];
        u16x4 ev[8], gv[8];
#pragma unroll
        for (int k = 0; k < 8; ++k)
            if (k < m) ss[k] = srcs[t + k];
#pragma unroll
        for (int k = 0; k < 8; ++k)
            if (k < m) {
                ev[k] = *reinterpret_cast<const u16x4*>(ea_s + (size_t)(t + k) * HID + c);
                gv[k] = *reinterpret_cast<const u16x4*>(hb + (size_t)ss[k] * HID + c);
            }
#pragma unroll
        for (int k = 0; k < 8; ++k)
            if (k < m) {
                a0 += fmaxf(b2f(ev[k][0]) + b2f(gv[k][0]), 0.f);
                a1 += fmaxf(b2f(ev[k][1]) + b2f(gv[k][1]), 0.f);
                a2 += fmaxf(b2f(ev[k][2]) + b2f(gv[k][2]), 0.f);
                a3 += fmaxf(b2f(ev[k][3]) + b2f(gv[k][3]), 0.f);
            }
    }
    u16x4 o;
    o[0] = (unsigned short)f2b(a0);
    o[1] = (unsigned short)f2b(a1);
    o[2] = (unsigned short)f2b(a2);
    o[3] = (unsigned short)f2b(a3);
    *reinterpret_cast<u16x4*>(zb + (size_t)n * HID + c) = o;
}

// ----------------------------------------------------------- bf16 MFMA GEMM
// C[M,256] = act(A@W + bias). BM=256 (4 waves x 64 rows), BN=64, K=256.
// XCD-chunked swizzle; B panel (32KB) in LDS (XOR swizzle); depth-1 A
// prefetch; LDS-transposed coalesced epilogue; optional fused BN stats.
template <bool RELU, bool STATS>
__global__ __launch_bounds__(256, 3) void gemm_k(const short* __restrict__ A,
                                                 const short* __restrict__ wT,
                                                 const float* __restrict__ bias,
                                                 short* __restrict__ C,
                                                 float* __restrict__ stats, int M) {
    __shared__ short Bs[64 * 256]; // 32KB
    char* BsB = (char*)Bs;
    int wv = threadIdx.x >> 6, lane = threadIdx.x & 63;
    int lr = lane & 15, lg = lane >> 4;

    // XCD-chunked swizzle (grid 784 = 8 * 98)
    int bid = blockIdx.x;
    int sw = (bid & 7) * (gridDim.x >> 3) + (bid >> 3);
    int c0 = (sw & 3) * 64;
    int r0 = (sw >> 2) * 256 + wv * 64;

    const char* panel = (const char*)(wT + (size_t)c0 * 256);
    {
        float4 v[4];
#pragma unroll
        for (int it = 0; it < 4; ++it)
            v[it] = *reinterpret_cast<const float4*>(panel + (threadIdx.x + it * 256) * 16);
#pragma unroll
        for (int it = 0; it < 4; ++it) {
            int o = (threadIdx.x + it * 256) * 16;
            int n = o >> 9;
            *reinterpret_cast<float4*>(BsB + (o ^ ((n & 7) << 4))) = v[it];
        }
        float4 v2[4];
#pragma unroll
        for (int it = 4; it < 8; ++it)
            v2[it - 4] = *reinterpret_cast<const float4*>(panel + (threadIdx.x + it * 256) * 16);
#pragma unroll
        for (int it = 4; it < 8; ++it) {
            int o = (threadIdx.x + it * 256) * 16;
            int n = o >> 9;
            *reinterpret_cast<float4*>(BsB + (o ^ ((n & 7) << 4))) = v2[it - 4];
        }
    }

    const short* pA[4];
    bool gok[4];
#pragma unroll
    for (int f = 0; f < 4; ++f) {
        int r = r0 + f * 16 + lr;
        gok[f] = r < M;
        pA[f] = A + (size_t)r * 256 + lg * 8;
    }

    f32x4 acc[4][4] = {};
    bf16x8 aCur[4] = {}, aNxt[4] = {};
#pragma unroll
    for (int f = 0; f < 4; ++f)
        if (gok[f]) aCur[f] = *reinterpret_cast<const bf16x8*>(pA[f]);

    __syncthreads();

    for (int k0 = 0; k0 < 256; k0 += 32) {
        if (k0 < 224) {
#pragma unroll
            for (int f = 0; f < 4; ++f)
                if (gok[f]) aNxt[f] = *reinterpret_cast<const bf16x8*>(pA[f] + k0 + 32);
        }
#pragma unroll
        for (int cc = 0; cc < 4; ++cc) {
            int n = cc * 16 + lr;
            int kb = k0 * 2 + lg * 16;
            bf16x8 b = *reinterpret_cast<const bf16x8*>(
                BsB + ((n * 512 + (kb ^ ((n & 7) << 4)))));
#pragma unroll
            for (int f = 0; f < 4; ++f)
                acc[f][cc] = __builtin_amdgcn_mfma_f32_16x16x32_bf16(aCur[f], b, acc[f][cc], 0, 0, 0);
        }
#pragma unroll
        for (int f = 0; f < 4; ++f) aCur[f] = aNxt[f];
    }

    __syncthreads();
    char* S = BsB + wv * 8192;
#pragma unroll
    for (int cc = 0; cc < 4; ++cc) {
        int colL = cc * 16 + lr;
        float bi = bias[c0 + colL];
        float s = 0.f, ss2 = 0.f;
#pragma unroll
        for (int f = 0; f < 4; ++f)
#pragma unroll
            for (int i = 0; i < 4; ++i) {
                int rowL = f * 16 + lg * 4 + i;
                float v = acc[f][cc][i] + bi;
                if (RELU) v = fmaxf(v, 0.f);
                if (STATS && (r0 + rowL) < M) { s += v; ss2 = fmaf(v, v, ss2); }
                int byte = rowL * 128 + ((colL * 2) ^ ((rowL & 7) << 4));
                *reinterpret_cast<short*>(S + byte) = f2b(v);
            }
        if (STATS) {
            s   += __shfl_xor(s, 16);  ss2 += __shfl_xor(ss2, 16);
            s   += __shfl_xor(s, 32);  ss2 += __shfl_xor(ss2, 32);
            if (lg == 0) {
                atomicAdd(&stats[c0 + colL], s);
                atomicAdd(&stats[HID + c0 + colL], ss2);
            }
        }
    }
    asm volatile("s_waitcnt lgkmcnt(0)" ::: "memory");
#pragma unroll
    for (int j = 0; j < 8; ++j) {
        int rowL = j * 8 + (lane >> 3);
        int cb = (lane & 7) * 16;
        int byte = rowL * 128 + (cb ^ ((rowL & 7) << 4));
        int4 d = *reinterpret_cast<const int4*>(S + byte);
        int grow = r0 + rowL;
        if (grow < M)
            *reinterpret_cast<int4*>((char*)C + (size_t)grow * 512 + c0 * 2 + cb) = d;
    }
}

// ------------------------------------------------------- BN normalize+relu
__global__ void bn_relu_k(const short* __restrict__ z, short* __restrict__ hb,
                          const float* __restrict__ stats,
                          const float* __restrict__ gamma,
                          const float* __restrict__ beta) {
    int gidx = blockIdx.x * 256 + threadIdx.x;
    int base = gidx * 4;
    int j = base & 255;
    u16x4 z4 = *reinterpret_cast<const u16x4*>(z + base);
    u16x4 o;
#pragma unroll
    for (int i = 0; i < 4; ++i) {
        float mu  = stats[j + i] * (1.f / NNODES);
        float var = stats[HID + j + i] * (1.f / NNODES) - mu * mu;
        float inv = rsqrtf(var + 1e-5f);
        float v = (b2f(z4[i]) - mu) * inv * gamma[j + i] + beta[j + i];
        o[i] = (unsigned short)f2b(fmaxf(v, 0.f));
    }
    *reinterpret_cast<u16x4*>(hb + base) = o;
}

// ------------------------------------------------------------------ pool
#define PNB 64
__global__ void pool_k(const short* __restrict__ hb, const int* __restrict__ batch,
                       float* __restrict__ g) {
    int j = threadIdx.x;
    int n0 = blockIdx.x * PNB;
    int n1 = min(n0 + PNB, NNODES);
    int cur = batch[n0];
    float acc = 0.f;
    for (int n = n0; n < n1; ++n) {
        int b = batch[n];
        if (b != cur) {
            atomicAdd(&g[(size_t)cur * HID + j], acc);
            acc = 0.f; cur = b;
        }
        acc += b2f((unsigned short)hb[(size_t)n * HID + j]);
    }
    atomicAdd(&g[(size_t)cur * HID + j], acc);
}

// ------------------------------------------------------------------ head
__global__ void head_k(const float* __restrict__ g, const float* __restrict__ w1,
                       const float* __restrict__ b1, const float* __restrict__ w2,
                       const float* __restrict__ b2, float* __restrict__ out) {
    int gi = blockIdx.x;
    int j  = threadIdx.x;
    __shared__ float gr[256];
    __shared__ float hid[128];
    gr[j]       = g[gi * 256 + j];
    gr[j + 128] = g[gi * 256 + 128 + j];
    __syncthreads();
    float acc = b1[j];
    for (int k = 0; k < 256; ++k) acc = fmaf(gr[k], w1[k * 128 + j], acc);
    hid[j] = fmaxf(acc, 0.f);
    __syncthreads();
    if (j < 12) {
        float o = b2[j];
#pragma unroll
        for (int k = 0; k < 128; ++k) o = fmaf(hid[k], w2[k * 12 + j], o);
        out[gi * 12 + j] = o;
    }
}

// ---------------------------------------------------------------- launch
extern "C" void kernel_launch(void* const* d_in, const int* in_sizes, int n_in,
                              void* d_out, int out_size, void* d_ws, size_t ws_size,
                              hipStream_t stream) {
    const float* x     = (const float*)d_in[0];
    const int*   ei    = (const int*)d_in[1];
    const int*   batch = (const int*)d_in[2];
    const float* eattr = (const float*)d_in[3];
    const float* nw    = (const float*)d_in[4];
    const float* nb    = (const float*)d_in[5];
    const float* ew    = (const float*)d_in[6];
    const float* eb    = (const float*)d_in[7];
    const float* w1    = (const float*)d_in[8];
    const float* b1    = (const float*)d_in[9];
    const float* w2    = (const float*)d_in[10];
    const float* b2    = (const float*)d_in[11];
    const float* gam   = (const float*)d_in[12];
    const float* bet   = (const float*)d_in[13];
    const float* hw1   = (const float*)d_in[14];
    const float* hb1   = (const float*)d_in[15];
    const float* hw2   = (const float*)d_in[16];
    const float* hb2   = (const float*)d_in[17];
    float* out = (float*)d_out;

    const size_t NH = (size_t)NNODES * HID;
    const size_t EH = (size_t)NEDGES * HID;
    size_t off = 0;
    char* base = (char*)d_ws;
    auto alloc = [&](size_t bytes) -> void* {
        void* p = base + off;
        off += (bytes + 255) & ~(size_t)255;
        return p;
    };
    short* hb      = (short*)alloc(NH * 2);
    short* zb      = (short*)alloc(NH * 2);
    short* z1b     = (short*)alloc(NH * 2);
    short* wT      = (short*)alloc(8 * 65536 * 2);
    short* ea_s    = (short*)alloc(EH * 2);       // 153.6 MB, layer-invariant
    float* eattr_s = (float*)alloc((size_t)NEDGES * 16 * 4); // 19.2 MB slot-ordered
    int*   srcs    = (int*)alloc((size_t)NEDGES * 4);
    float* stats   = (float*)alloc(512 * 4);
    float* g       = (float*)alloc((size_t)NGRAPHS * HID * 4);
    int*   deg     = (int*)alloc((size_t)NNODES * 4);
    int*   partial = (int*)alloc((size_t)NNODES * 4);
    int*   btot    = (int*)alloc(256 * 4);
    int*   row_ptr = (int*)alloc((size_t)(NNODES + 1) * 4);
    int*   cursor  = (int*)alloc((size_t)NNODES * 4);
    int*   slot    = (int*)alloc((size_t)NEDGES * 4);

    wconv_k<<<dim3(256, 4), 256, 0, stream>>>(w1, wT);
    wconv_k<<<dim3(256, 4), 256, 0, stream>>>(w2, wT + 4 * 65536);
    node_embed_k<<<NNODES, 256, 0, stream>>>(x, nw, nb, hb);

    hipMemsetAsync(deg, 0, (size_t)NNODES * 4, stream);
    deg_k<<<(NEDGES + 255) / 256, 256, 0, stream>>>(ei, deg);
    const int NB = (NNODES + 255) / 256;
    scan1_k<<<NB, 256, 0, stream>>>(deg, partial, btot);
    scan2_k<<<1, 256, 0, stream>>>(btot, NB);
    scan3_k<<<NB, 256, 0, stream>>>(deg, partial, btot, row_ptr, cursor);
    fill_k<<<(NEDGES + 255) / 256, 256, 0, stream>>>(ei, cursor, slot, srcs);
    esort3_k<<<(NEDGES + 63) / 64, 256, 0, stream>>>(eattr, slot, eattr_s);
    ea_k<<<NEDGES / 16, 256, 0, stream>>>(eattr_s, ew, eb, ea_s);

    const int GG = ((NNODES + 255) / 256) * 4;   // 784, %8==0
    for (int l = 0; l < L; ++l) {
        agg_k<<<NNODES / 4, 256, 0, stream>>>(
            hb, ea_s, srcs, row_ptr, zb, stats);
        gemm_k<true, false><<<GG, 256, 0, stream>>>(
            zb, wT + (size_t)l * 65536, b1 + l * HID, z1b, nullptr, NNODES);
        gemm_k<false, true><<<GG, 256, 0, stream>>>(
            z1b, wT + (size_t)(4 + l) * 65536, b2 + l * HID, zb, stats, NNODES);
        bn_relu_k<<<(int)(NH / 1024), 256, 0, stream>>>(
            zb, hb, stats, gam + l * HID, bet + l * HID);
    }

    hipMemsetAsync(g, 0, (size_t)NGRAPHS * HID * 4, stream);
    pool_k<<<(NNODES + PNB - 1) / PNB, 256, 0, stream>>>(hb, batch, g);
    head_k<<<NGRAPHS, 128, 0, stream>>>(g, hw1, hb1, hw2, hb2, out);
}

// Round 11
// 832.366 us; speedup vs baseline: 1.1264x; 1.0039x over previous
//
#include <hip/hip_runtime.h>
#include <hip/hip_bf16.h>

#define HID     256
#define NNODES  50000
#define NEDGES  300000
#define NGRAPHS 128
#define L       4

typedef __attribute__((ext_vector_type(8))) short bf16x8;
typedef __attribute__((ext_vector_type(4))) float f32x4;
typedef __attribute__((ext_vector_type(4))) unsigned short u16x4;

static __device__ __forceinline__ float b2f(unsigned short s) {
    union { unsigned u; float f; } v;
    v.u = ((unsigned)s) << 16;
    return v.f;
}
static __device__ __forceinline__ short f2b(float f) {
    __hip_bfloat16 h = __float2bfloat16(f);
    return *reinterpret_cast<short*>(&h);
}

// ------------------------------------------------ weight convert + transpose
__global__ void wconv_k(const float* __restrict__ w, short* __restrict__ wT) {
    int m = blockIdx.y, n = blockIdx.x, k = threadIdx.x;
    wT[(size_t)m * 65536 + n * 256 + k] = f2b(w[(size_t)m * 65536 + k * 256 + n]);
}

// ---------------------------------------------------------------- node embed
__global__ void node_embed_k(const float* __restrict__ x,
                             const float* __restrict__ w,
                             const float* __restrict__ b,
                             short* __restrict__ hb) {
    int n = blockIdx.x;
    int j = threadIdx.x;
    __shared__ float xr[32];
    if (j < 32) xr[j] = x[n * 32 + j];
    __syncthreads();
    float acc = b[j];
#pragma unroll
    for (int k = 0; k < 32; ++k) acc = fmaf(xr[k], w[k * HID + j], acc);
    hb[(size_t)n * HID + j] = f2b(acc);
}

// ------------------------------------------------------------- CSR building
__global__ void deg_k(const int* __restrict__ ei, int* __restrict__ deg) {
    int e = blockIdx.x * 256 + threadIdx.x;
    if (e < NEDGES) atomicAdd(&deg[ei[NEDGES + e]], 1);
}

__global__ void scan1_k(const int* __restrict__ deg, int* __restrict__ partial,
                        int* __restrict__ btot) {
    __shared__ int s[256];
    int t = threadIdx.x;
    int gi = blockIdx.x * 256 + t;
    s[t] = (gi < NNODES) ? deg[gi] : 0;
    __syncthreads();
    for (int off = 1; off < 256; off <<= 1) {
        int u = (t >= off) ? s[t - off] : 0;
        __syncthreads();
        s[t] += u;
        __syncthreads();
    }
    if (gi < NNODES) partial[gi] = s[t];
    if (t == 255) btot[blockIdx.x] = s[255];
}

__global__ void scan2_k(int* __restrict__ btot, int nb) {
    __shared__ int s[256];
    int t = threadIdx.x;
    s[t] = (t < nb) ? btot[t] : 0;
    __syncthreads();
    for (int off = 1; off < 256; off <<= 1) {
        int u = (t >= off) ? s[t - off] : 0;
        __syncthreads();
        s[t] += u;
        __syncthreads();
    }
    btot[t] = s[t];
}

__global__ void scan3_k(const int* __restrict__ deg, const int* __restrict__ partial,
                        const int* __restrict__ btot, int* __restrict__ row_ptr,
                        int* __restrict__ cursor) {
    int gi = blockIdx.x * 256 + threadIdx.x;
    if (gi >= NNODES) return;
    int b = blockIdx.x;
    int incl = partial[gi] + (b ? btot[b - 1] : 0);
    int start = incl - deg[gi];
    row_ptr[gi] = start;
    cursor[gi] = start;
    if (gi == NNODES - 1) row_ptr[NNODES] = incl;
}

// fill: slot[e] = CSR position of edge e; srcs[pos] = src node (scatter).
__global__ void fill_k(const int* __restrict__ ei, int* __restrict__ cursor,
                       int* __restrict__ slot, int* __restrict__ srcs) {
    int e = blockIdx.x * 256 + threadIdx.x;
    if (e < NEDGES) {
        int d = ei[NEDGES + e];
        int pos = atomicAdd(&cursor[d], 1);
        slot[e] = pos;
        srcs[pos] = ei[e];
    }
}

// ---------- scatter the SMALL payload: eattr_s[slot[e]] = eattr[e] (fp32 64B)
__global__ void esort3_k(const float* __restrict__ eattr, const int* __restrict__ slot,
                         float* __restrict__ eattr_s) {
    int e = blockIdx.x * 64 + (threadIdx.x >> 2);   // 64 edges per block
    int q = threadIdx.x & 3;                        // 4 lanes per edge (16B each)
    if (e < NEDGES) {
        float4 v = reinterpret_cast<const float4*>(eattr + (size_t)e * 16)[q];
        reinterpret_cast<float4*>(eattr_s + (size_t)slot[e] * 16)[q] = v;
    }
}

// ---------------- one-time: ea_s[t] = bf16(eattr_s[t] @ ew + eb)
// Both sides streaming. __launch_bounds__(256,2): allow ~256 VGPR so the
// compiler KEEPS the 16x4 weight block register-resident (round-10 profile
// showed VGPR_Count=52 -> weights were re-loaded from cache per edge).
#define FMA4(mm, s, wv4) do { \
    mm.x = fmaf((s), (wv4).x, mm.x); \
    mm.y = fmaf((s), (wv4).y, mm.y); \
    mm.z = fmaf((s), (wv4).z, mm.z); \
    mm.w = fmaf((s), (wv4).w, mm.w); } while (0)

__global__ __launch_bounds__(256, 2) void ea_k(const float* __restrict__ eattr_s,
                                               const float* __restrict__ ew,
                                               const float* __restrict__ ebias,
                                               short* __restrict__ ea_s) {
    int lane = threadIdx.x & 63, wv = threadIdx.x >> 6;
    int c = lane * 4;
    float4 w0  = *reinterpret_cast<const float4*>(ew + 0 * 256 + c);
    float4 w1  = *reinterpret_cast<const float4*>(ew + 1 * 256 + c);
    float4 w2  = *reinterpret_cast<const float4*>(ew + 2 * 256 + c);
    float4 w3  = *reinterpret_cast<const float4*>(ew + 3 * 256 + c);
    float4 w4  = *reinterpret_cast<const float4*>(ew + 4 * 256 + c);
    float4 w5  = *reinterpret_cast<const float4*>(ew + 5 * 256 + c);
    float4 w6  = *reinterpret_cast<const float4*>(ew + 6 * 256 + c);
    float4 w7  = *reinterpret_cast<const float4*>(ew + 7 * 256 + c);
    float4 w8  = *reinterpret_cast<const float4*>(ew + 8 * 256 + c);
    float4 w9  = *reinterpret_cast<const float4*>(ew + 9 * 256 + c);
    float4 w10 = *reinterpret_cast<const float4*>(ew + 10 * 256 + c);
    float4 w11 = *reinterpret_cast<const float4*>(ew + 11 * 256 + c);
    float4 w12 = *reinterpret_cast<const float4*>(ew + 12 * 256 + c);
    float4 w13 = *reinterpret_cast<const float4*>(ew + 13 * 256 + c);
    float4 w14 = *reinterpret_cast<const float4*>(ew + 14 * 256 + c);
    float4 w15 = *reinterpret_cast<const float4*>(ew + 15 * 256 + c);
    float4 ebv = *reinterpret_cast<const float4*>(ebias + c);

    int t0 = (blockIdx.x * 4 + wv) * 4;
    if (t0 >= NEDGES) return;
    float4 q[4][4];
#pragma unroll
    for (int j = 0; j < 4; ++j) {
        const float4* ep = reinterpret_cast<const float4*>(eattr_s + (size_t)(t0 + j) * 16);
        q[j][0] = ep[0]; q[j][1] = ep[1]; q[j][2] = ep[2]; q[j][3] = ep[3];
    }
#pragma unroll
    for (int j = 0; j < 4; ++j) {
        float4 m = ebv;
        FMA4(m, q[j][0].x, w0);  FMA4(m, q[j][0].y, w1);
        FMA4(m, q[j][0].z, w2);  FMA4(m, q[j][0].w, w3);
        FMA4(m, q[j][1].x, w4);  FMA4(m, q[j][1].y, w5);
        FMA4(m, q[j][1].z, w6);  FMA4(m, q[j][1].w, w7);
        FMA4(m, q[j][2].x, w8);  FMA4(m, q[j][2].y, w9);
        FMA4(m, q[j][2].z, w10); FMA4(m, q[j][2].w, w11);
        FMA4(m, q[j][3].x, w12); FMA4(m, q[j][3].y, w13);
        FMA4(m, q[j][3].z, w14); FMA4(m, q[j][3].w, w15);
        u16x4 o;
        o[0] = (unsigned short)f2b(m.x);
        o[1] = (unsigned short)f2b(m.y);
        o[2] = (unsigned short)f2b(m.z);
        o[3] = (unsigned short)f2b(m.w);
        *reinterpret_cast<u16x4*>(ea_s + (size_t)(t0 + j) * HID + c) = o;
    }
}

// ------------------------------------------------- CSR aggregate, wave-per-node
// zb[n] = hb[n] + sum_t relu(hb[srcs[t]] + ea_s[t]); one wave per node,
// window of 8 edges (16 loads in flight). Block 0 zeroes BN stats.
__global__ __launch_bounds__(256) void agg_k(
    const short* __restrict__ hb, const short* __restrict__ ea_s,
    const int* __restrict__ srcs, const int* __restrict__ row_ptr,
    short* __restrict__ zb, float* __restrict__ stats) {
    if (blockIdx.x == 0) {
        stats[threadIdx.x] = 0.f;
        stats[threadIdx.x + 256] = 0.f;
    }
    int lane = threadIdx.x & 63, wv = threadIdx.x >> 6;
    int c = lane * 4;
    int n = blockIdx.x * 4 + wv;          // grid exact: 12500*4 = 50000
    int beg = row_ptr[n], end = row_ptr[n + 1];
    u16x4 h4 = *reinterpret_cast<const u16x4*>(hb + (size_t)n * HID + c);
    float a0 = b2f(h4[0]), a1 = b2f(h4[1]), a2 = b2f(h4[2]), a3 = b2f(h4[3]);

    for (int t = beg; t < end; t += 8) {
        int m = min(8, end - t);
        int ss[8];
        u16x4 ev[8], gv[8];
#pragma unroll
        for (int k = 0; k < 8; ++k)
            if (k < m) ss[k] = srcs[t + k];
#pragma unroll
        for (int k = 0; k < 8; ++k)
            if (k < m) {
                ev[k] = *reinterpret_cast<const u16x4*>(ea_s + (size_t)(t + k) * HID + c);
                gv[k] = *reinterpret_cast<const u16x4*>(hb + (size_t)ss[k] * HID + c);
            }
#pragma unroll
        for (int k = 0; k < 8; ++k)
            if (k < m) {
                a0 += fmaxf(b2f(ev[k][0]) + b2f(gv[k][0]), 0.f);
                a1 += fmaxf(b2f(ev[k][1]) + b2f(gv[k][1]), 0.f);
                a2 += fmaxf(b2f(ev[k][2]) + b2f(gv[k][2]), 0.f);
                a3 += fmaxf(b2f(ev[k][3]) + b2f(gv[k][3]), 0.f);
            }
    }
    u16x4 o;
    o[0] = (unsigned short)f2b(a0);
    o[1] = (unsigned short)f2b(a1);
    o[2] = (unsigned short)f2b(a2);
    o[3] = (unsigned short)f2b(a3);
    *reinterpret_cast<u16x4*>(zb + (size_t)n * HID + c) = o;
}

// ----------------------------------------------------------- bf16 MFMA GEMM
// C[M,256] = act(A@W + bias). BM=256 (4 waves x 64 rows), BN=64, K=256.
// XCD-chunked swizzle; B panel (32KB) in LDS (XOR swizzle); depth-1 A
// prefetch; LDS-transposed coalesced epilogue; optional fused BN stats.
template <bool RELU, bool STATS>
__global__ __launch_bounds__(256, 3) void gemm_k(const short* __restrict__ A,
                                                 const short* __restrict__ wT,
                                                 const float* __restrict__ bias,
                                                 short* __restrict__ C,
                                                 float* __restrict__ stats, int M) {
    __shared__ short Bs[64 * 256]; // 32KB
    char* BsB = (char*)Bs;
    int wv = threadIdx.x >> 6, lane = threadIdx.x & 63;
    int lr = lane & 15, lg = lane >> 4;

    // XCD-chunked swizzle (grid 784 = 8 * 98)
    int bid = blockIdx.x;
    int sw = (bid & 7) * (gridDim.x >> 3) + (bid >> 3);
    int c0 = (sw & 3) * 64;
    int r0 = (sw >> 2) * 256 + wv * 64;

    const char* panel = (const char*)(wT + (size_t)c0 * 256);
    {
        float4 v[4];
#pragma unroll
        for (int it = 0; it < 4; ++it)
            v[it] = *reinterpret_cast<const float4*>(panel + (threadIdx.x + it * 256) * 16);
#pragma unroll
        for (int it = 0; it < 4; ++it) {
            int o = (threadIdx.x + it * 256) * 16;
            int n = o >> 9;
            *reinterpret_cast<float4*>(BsB + (o ^ ((n & 7) << 4))) = v[it];
        }
        float4 v2[4];
#pragma unroll
        for (int it = 4; it < 8; ++it)
            v2[it - 4] = *reinterpret_cast<const float4*>(panel + (threadIdx.x + it * 256) * 16);
#pragma unroll
        for (int it = 4; it < 8; ++it) {
            int o = (threadIdx.x + it * 256) * 16;
            int n = o >> 9;
            *reinterpret_cast<float4*>(BsB + (o ^ ((n & 7) << 4))) = v2[it - 4];
        }
    }

    const short* pA[4];
    bool gok[4];
#pragma unroll
    for (int f = 0; f < 4; ++f) {
        int r = r0 + f * 16 + lr;
        gok[f] = r < M;
        pA[f] = A + (size_t)r * 256 + lg * 8;
    }

    f32x4 acc[4][4] = {};
    bf16x8 aCur[4] = {}, aNxt[4] = {};
#pragma unroll
    for (int f = 0; f < 4; ++f)
        if (gok[f]) aCur[f] = *reinterpret_cast<const bf16x8*>(pA[f]);

    __syncthreads();

    for (int k0 = 0; k0 < 256; k0 += 32) {
        if (k0 < 224) {
#pragma unroll
            for (int f = 0; f < 4; ++f)
                if (gok[f]) aNxt[f] = *reinterpret_cast<const bf16x8*>(pA[f] + k0 + 32);
        }
#pragma unroll
        for (int cc = 0; cc < 4; ++cc) {
            int n = cc * 16 + lr;
            int kb = k0 * 2 + lg * 16;
            bf16x8 b = *reinterpret_cast<const bf16x8*>(
                BsB + ((n * 512 + (kb ^ ((n & 7) << 4)))));
#pragma unroll
            for (int f = 0; f < 4; ++f)
                acc[f][cc] = __builtin_amdgcn_mfma_f32_16x16x32_bf16(aCur[f], b, acc[f][cc], 0, 0, 0);
        }
#pragma unroll
        for (int f = 0; f < 4; ++f) aCur[f] = aNxt[f];
    }

    __syncthreads();
    char* S = BsB + wv * 8192;
#pragma unroll
    for (int cc = 0; cc < 4; ++cc) {
        int colL = cc * 16 + lr;
        float bi = bias[c0 + colL];
        float s = 0.f, ss2 = 0.f;
#pragma unroll
        for (int f = 0; f < 4; ++f)
#pragma unroll
            for (int i = 0; i < 4; ++i) {
                int rowL = f * 16 + lg * 4 + i;
                float v = acc[f][cc][i] + bi;
                if (RELU) v = fmaxf(v, 0.f);
                if (STATS && (r0 + rowL) < M) { s += v; ss2 = fmaf(v, v, ss2); }
                int byte = rowL * 128 + ((colL * 2) ^ ((rowL & 7) << 4));
                *reinterpret_cast<short*>(S + byte) = f2b(v);
            }
        if (STATS) {
            s   += __shfl_xor(s, 16);  ss2 += __shfl_xor(ss2, 16);
            s   += __shfl_xor(s, 32);  ss2 += __shfl_xor(ss2, 32);
            if (lg == 0) {
                atomicAdd(&stats[c0 + colL], s);
                atomicAdd(&stats[HID + c0 + colL], ss2);
            }
        }
    }
    asm volatile("s_waitcnt lgkmcnt(0)" ::: "memory");
#pragma unroll
    for (int j = 0; j < 8; ++j) {
        int rowL = j * 8 + (lane >> 3);
        int cb = (lane & 7) * 16;
        int byte = rowL * 128 + (cb ^ ((rowL & 7) << 4));
        int4 d = *reinterpret_cast<const int4*>(S + byte);
        int grow = r0 + rowL;
        if (grow < M)
            *reinterpret_cast<int4*>((char*)C + (size_t)grow * 512 + c0 * 2 + cb) = d;
    }
}

// ------------------------------------------------------- BN normalize+relu
__global__ void bn_relu_k(const short* __restrict__ z, short* __restrict__ hb,
                          const float* __restrict__ stats,
                          const float* __restrict__ gamma,
                          const float* __restrict__ beta) {
    int gidx = blockIdx.x * 256 + threadIdx.x;
    int base = gidx * 4;
    int j = base & 255;
    u16x4 z4 = *reinterpret_cast<const u16x4*>(z + base);
    u16x4 o;
#pragma unroll
    for (int i = 0; i < 4; ++i) {
        float mu  = stats[j + i] * (1.f / NNODES);
        float var = stats[HID + j + i] * (1.f / NNODES) - mu * mu;
        float inv = rsqrtf(var + 1e-5f);
        float v = (b2f(z4[i]) - mu) * inv * gamma[j + i] + beta[j + i];
        o[i] = (unsigned short)f2b(fmaxf(v, 0.f));
    }
    *reinterpret_cast<u16x4*>(hb + base) = o;
}

// ------------------------------------------------------------------ pool
#define PNB 64
__global__ void pool_k(const short* __restrict__ hb, const int* __restrict__ batch,
                       float* __restrict__ g) {
    int j = threadIdx.x;
    int n0 = blockIdx.x * PNB;
    int n1 = min(n0 + PNB, NNODES);
    int cur = batch[n0];
    float acc = 0.f;
    for (int n = n0; n < n1; ++n) {
        int b = batch[n];
        if (b != cur) {
            atomicAdd(&g[(size_t)cur * HID + j], acc);
            acc = 0.f; cur = b;
        }
        acc += b2f((unsigned short)hb[(size_t)n * HID + j]);
    }
    atomicAdd(&g[(size_t)cur * HID + j], acc);
}

// ------------------------------------------------------------------ head
__global__ void head_k(const float* __restrict__ g, const float* __restrict__ w1,
                       const float* __restrict__ b1, const float* __restrict__ w2,
                       const float* __restrict__ b2, float* __restrict__ out) {
    int gi = blockIdx.x;
    int j  = threadIdx.x;
    __shared__ float gr[256];
    __shared__ float hid[128];
    gr[j]       = g[gi * 256 + j];
    gr[j + 128] = g[gi * 256 + 128 + j];
    __syncthreads();
    float acc = b1[j];
    for (int k = 0; k < 256; ++k) acc = fmaf(gr[k], w1[k * 128 + j], acc);
    hid[j] = fmaxf(acc, 0.f);
    __syncthreads();
    if (j < 12) {
        float o = b2[j];
#pragma unroll
        for (int k = 0; k < 128; ++k) o = fmaf(hid[k], w2[k * 12 + j], o);
        out[gi * 12 + j] = o;
    }
}

// ---------------------------------------------------------------- launch
extern "C" void kernel_launch(void* const* d_in, const int* in_sizes, int n_in,
                              void* d_out, int out_size, void* d_ws, size_t ws_size,
                              hipStream_t stream) {
    const float* x     = (const float*)d_in[0];
    const int*   ei    = (const int*)d_in[1];
    const int*   batch = (const int*)d_in[2];
    const float* eattr = (const float*)d_in[3];
    const float* nw    = (const float*)d_in[4];
    const float* nb    = (const float*)d_in[5];
    const float* ew    = (const float*)d_in[6];
    const float* eb    = (const float*)d_in[7];
    const float* w1    = (const float*)d_in[8];
    const float* b1    = (const float*)d_in[9];
    const float* w2    = (const float*)d_in[10];
    const float* b2    = (const float*)d_in[11];
    const float* gam   = (const float*)d_in[12];
    const float* bet   = (const float*)d_in[13];
    const float* hw1   = (const float*)d_in[14];
    const float* hb1   = (const float*)d_in[15];
    const float* hw2   = (const float*)d_in[16];
    const float* hb2   = (const float*)d_in[17];
    float* out = (float*)d_out;

    const size_t NH = (size_t)NNODES * HID;
    const size_t EH = (size_t)NEDGES * HID;
    size_t off = 0;
    char* base = (char*)d_ws;
    auto alloc = [&](size_t bytes) -> void* {
        void* p = base + off;
        off += (bytes + 255) & ~(size_t)255;
        return p;
    };
    short* hb      = (short*)alloc(NH * 2);
    short* zb      = (short*)alloc(NH * 2);
    short* z1b     = (short*)alloc(NH * 2);
    short* wT      = (short*)alloc(8 * 65536 * 2);
    short* ea_s    = (short*)alloc(EH * 2);       // 153.6 MB, layer-invariant
    float* eattr_s = (float*)alloc((size_t)NEDGES * 16 * 4); // 19.2 MB slot-ordered
    int*   srcs    = (int*)alloc((size_t)NEDGES * 4);
    float* stats   = (float*)alloc(512 * 4);
    float* g       = (float*)alloc((size_t)NGRAPHS * HID * 4);
    int*   deg     = (int*)alloc((size_t)NNODES * 4);
    int*   partial = (int*)alloc((size_t)NNODES * 4);
    int*   btot    = (int*)alloc(256 * 4);
    int*   row_ptr = (int*)alloc((size_t)(NNODES + 1) * 4);
    int*   cursor  = (int*)alloc((size_t)NNODES * 4);
    int*   slot    = (int*)alloc((size_t)NEDGES * 4);

    wconv_k<<<dim3(256, 4), 256, 0, stream>>>(w1, wT);
    wconv_k<<<dim3(256, 4), 256, 0, stream>>>(w2, wT + 4 * 65536);
    node_embed_k<<<NNODES, 256, 0, stream>>>(x, nw, nb, hb);

    hipMemsetAsync(deg, 0, (size_t)NNODES * 4, stream);
    deg_k<<<(NEDGES + 255) / 256, 256, 0, stream>>>(ei, deg);
    const int NB = (NNODES + 255) / 256;
    scan1_k<<<NB, 256, 0, stream>>>(deg, partial, btot);
    scan2_k<<<1, 256, 0, stream>>>(btot, NB);
    scan3_k<<<NB, 256, 0, stream>>>(deg, partial, btot, row_ptr, cursor);
    fill_k<<<(NEDGES + 255) / 256, 256, 0, stream>>>(ei, cursor, slot, srcs);
    esort3_k<<<(NEDGES + 63) / 64, 256, 0, stream>>>(eattr, slot, eattr_s);
    ea_k<<<NEDGES / 16, 256, 0, stream>>>(eattr_s, ew, eb, ea_s);

    const int GG = ((NNODES + 255) / 256) * 4;   // 784, %8==0
    for (int l = 0; l < L; ++l) {
        agg_k<<<NNODES / 4, 256, 0, stream>>>(
            hb, ea_s, srcs, row_ptr, zb, stats);
        gemm_k<true, false><<<GG, 256, 0, stream>>>(
            zb, wT + (size_t)l * 65536, b1 + l * HID, z1b, nullptr, NNODES);
        gemm_k<false, true><<<GG, 256, 0, stream>>>(
            z1b, wT + (size_t)(4 + l) * 65536, b2 + l * HID, zb, stats, NNODES);
        bn_relu_k<<<(int)(NH / 1024), 256, 0, stream>>>(
            zb, hb, stats, gam + l * HID, bet + l * HID);
    }

    hipMemsetAsync(g, 0, (size_t)NGRAPHS * HID * 4, stream);
    pool_k<<<(NNODES + PNB - 1) / PNB, 256, 0, stream>>>(hb, batch, g);
    head_k<<<NGRAPHS, 128, 0, stream>>>(g, hw1, hb1, hw2, hb2, out);
}

// Round 12
// 771.753 us; speedup vs baseline: 1.2149x; 1.0785x over previous
//
#include <hip/hip_runtime.h>
#include <hip/hip_bf16.h>

#define HID     256
#define NNODES  50000
#define NEDGES  300000
#define NGRAPHS 128
#define L       4

typedef __attribute__((ext_vector_type(8))) short bf16x8;
typedef __attribute__((ext_vector_type(4))) float f32x4;
typedef __attribute__((ext_vector_type(4))) unsigned short u16x4;

static __device__ __forceinline__ float b2f(unsigned short s) {
    union { unsigned u; float f; } v;
    v.u = ((unsigned)s) << 16;
    return v.f;
}
static __device__ __forceinline__ short f2b(float f) {
    __hip_bfloat16 h = __float2bfloat16(f);
    return *reinterpret_cast<short*>(&h);
}

// ------------------------------------------------ weight convert + transpose
__global__ void wconv_k(const float* __restrict__ w, short* __restrict__ wT) {
    int m = blockIdx.y, n = blockIdx.x, k = threadIdx.x;
    wT[(size_t)m * 65536 + n * 256 + k] = f2b(w[(size_t)m * 65536 + k * 256 + n]);
}

// ---------------------------------------------------------------- node embed
__global__ void node_embed_k(const float* __restrict__ x,
                             const float* __restrict__ w,
                             const float* __restrict__ b,
                             short* __restrict__ hb) {
    int n = blockIdx.x;
    int j = threadIdx.x;
    __shared__ float xr[32];
    if (j < 32) xr[j] = x[n * 32 + j];
    __syncthreads();
    float acc = b[j];
#pragma unroll
    for (int k = 0; k < 32; ++k) acc = fmaf(xr[k], w[k * HID + j], acc);
    hb[(size_t)n * HID + j] = f2b(acc);
}

// ------------------------------------------------------------- CSR building
__global__ void deg_k(const int* __restrict__ ei, int* __restrict__ deg) {
    int e = blockIdx.x * 256 + threadIdx.x;
    if (e < NEDGES) atomicAdd(&deg[ei[NEDGES + e]], 1);
}

__global__ void scan1_k(const int* __restrict__ deg, int* __restrict__ partial,
                        int* __restrict__ btot) {
    __shared__ int s[256];
    int t = threadIdx.x;
    int gi = blockIdx.x * 256 + t;
    s[t] = (gi < NNODES) ? deg[gi] : 0;
    __syncthreads();
    for (int off = 1; off < 256; off <<= 1) {
        int u = (t >= off) ? s[t - off] : 0;
        __syncthreads();
        s[t] += u;
        __syncthreads();
    }
    if (gi < NNODES) partial[gi] = s[t];
    if (t == 255) btot[blockIdx.x] = s[255];
}

__global__ void scan2_k(int* __restrict__ btot, int nb) {
    __shared__ int s[256];
    int t = threadIdx.x;
    s[t] = (t < nb) ? btot[t] : 0;
    __syncthreads();
    for (int off = 1; off < 256; off <<= 1) {
        int u = (t >= off) ? s[t - off] : 0;
        __syncthreads();
        s[t] += u;
        __syncthreads();
    }
    btot[t] = s[t];
}

__global__ void scan3_k(const int* __restrict__ deg, const int* __restrict__ partial,
                        const int* __restrict__ btot, int* __restrict__ row_ptr,
                        int* __restrict__ cursor) {
    int gi = blockIdx.x * 256 + threadIdx.x;
    if (gi >= NNODES) return;
    int b = blockIdx.x;
    int incl = partial[gi] + (b ? btot[b - 1] : 0);
    int start = incl - deg[gi];
    row_ptr[gi] = start;
    cursor[gi] = start;
    if (gi == NNODES - 1) row_ptr[NNODES] = incl;
}

// fill: slot[e] = CSR position of edge e; srcs[pos] = src node (scatter).
__global__ void fill_k(const int* __restrict__ ei, int* __restrict__ cursor,
                       int* __restrict__ slot, int* __restrict__ srcs) {
    int e = blockIdx.x * 256 + threadIdx.x;
    if (e < NEDGES) {
        int d = ei[NEDGES + e];
        int pos = atomicAdd(&cursor[d], 1);
        slot[e] = pos;
        srcs[pos] = ei[e];
    }
}

// ---------- scatter the SMALL payload: eattr_s[slot[e]] = eattr[e] (fp32 64B)
__global__ void esort3_k(const float* __restrict__ eattr, const int* __restrict__ slot,
                         float* __restrict__ eattr_s) {
    int e = blockIdx.x * 64 + (threadIdx.x >> 2);   // 64 edges per block
    int q = threadIdx.x & 3;                        // 4 lanes per edge (16B each)
    if (e < NEDGES) {
        float4 v = reinterpret_cast<const float4*>(eattr + (size_t)e * 16)[q];
        reinterpret_cast<float4*>(eattr_s + (size_t)slot[e] * 16)[q] = v;
    }
}

// ---------------- one-time: ea_s[t] = bf16(eattr_s[t] @ ew + eb)
// Both sides streaming. 16 edges per wave (4 groups of 4): amortizes the
// per-wave weight-block load 4x vs the 4-edge/wave version and keeps the
// store stream deep.
#define FMA4(mm, s, wv4) do { \
    mm.x = fmaf((s), (wv4).x, mm.x); \
    mm.y = fmaf((s), (wv4).y, mm.y); \
    mm.z = fmaf((s), (wv4).z, mm.z); \
    mm.w = fmaf((s), (wv4).w, mm.w); } while (0)

#define EA_EPW 16
__global__ __launch_bounds__(256) void ea_k(const float* __restrict__ eattr_s,
                                            const float* __restrict__ ew,
                                            const float* __restrict__ ebias,
                                            short* __restrict__ ea_s) {
    int lane = threadIdx.x & 63, wv = threadIdx.x >> 6;
    int c = lane * 4;
    float4 w0  = *reinterpret_cast<const float4*>(ew + 0 * 256 + c);
    float4 w1  = *reinterpret_cast<const float4*>(ew + 1 * 256 + c);
    float4 w2  = *reinterpret_cast<const float4*>(ew + 2 * 256 + c);
    float4 w3  = *reinterpret_cast<const float4*>(ew + 3 * 256 + c);
    float4 w4  = *reinterpret_cast<const float4*>(ew + 4 * 256 + c);
    float4 w5  = *reinterpret_cast<const float4*>(ew + 5 * 256 + c);
    float4 w6  = *reinterpret_cast<const float4*>(ew + 6 * 256 + c);
    float4 w7  = *reinterpret_cast<const float4*>(ew + 7 * 256 + c);
    float4 w8  = *reinterpret_cast<const float4*>(ew + 8 * 256 + c);
    float4 w9  = *reinterpret_cast<const float4*>(ew + 9 * 256 + c);
    float4 w10 = *reinterpret_cast<const float4*>(ew + 10 * 256 + c);
    float4 w11 = *reinterpret_cast<const float4*>(ew + 11 * 256 + c);
    float4 w12 = *reinterpret_cast<const float4*>(ew + 12 * 256 + c);
    float4 w13 = *reinterpret_cast<const float4*>(ew + 13 * 256 + c);
    float4 w14 = *reinterpret_cast<const float4*>(ew + 14 * 256 + c);
    float4 w15 = *reinterpret_cast<const float4*>(ew + 15 * 256 + c);
    float4 ebv = *reinterpret_cast<const float4*>(ebias + c);

    int tw = (blockIdx.x * 4 + wv) * EA_EPW;
    for (int t0 = tw; t0 < min(tw + EA_EPW, NEDGES); t0 += 4) {
        float4 q[4][4];
#pragma unroll
        for (int j = 0; j < 4; ++j) {
            const float4* ep = reinterpret_cast<const float4*>(eattr_s + (size_t)(t0 + j) * 16);
            q[j][0] = ep[0]; q[j][1] = ep[1]; q[j][2] = ep[2]; q[j][3] = ep[3];
        }
#pragma unroll
        for (int j = 0; j < 4; ++j) {
            float4 m = ebv;
            FMA4(m, q[j][0].x, w0);  FMA4(m, q[j][0].y, w1);
            FMA4(m, q[j][0].z, w2);  FMA4(m, q[j][0].w, w3);
            FMA4(m, q[j][1].x, w4);  FMA4(m, q[j][1].y, w5);
            FMA4(m, q[j][1].z, w6);  FMA4(m, q[j][1].w, w7);
            FMA4(m, q[j][2].x, w8);  FMA4(m, q[j][2].y, w9);
            FMA4(m, q[j][2].z, w10); FMA4(m, q[j][2].w, w11);
            FMA4(m, q[j][3].x, w12); FMA4(m, q[j][3].y, w13);
            FMA4(m, q[j][3].z, w14); FMA4(m, q[j][3].w, w15);
            u16x4 o;
            o[0] = (unsigned short)f2b(m.x);
            o[1] = (unsigned short)f2b(m.y);
            o[2] = (unsigned short)f2b(m.z);
            o[3] = (unsigned short)f2b(m.w);
            *reinterpret_cast<u16x4*>(ea_s + (size_t)(t0 + j) * HID + c) = o;
        }
    }
}

// --------------- BN prep: stats -> per-channel (scale, shift), re-zero stats
__global__ void bnprep_k(float* __restrict__ stats, const float* __restrict__ gamma,
                         const float* __restrict__ beta, float* __restrict__ ss) {
    int j = threadIdx.x;
    float mu  = stats[j] * (1.f / NNODES);
    float var = stats[256 + j] * (1.f / NNODES) - mu * mu;
    float sc  = rsqrtf(var + 1e-5f) * gamma[j];
    ss[j]       = sc;
    ss[256 + j] = beta[j] - mu * sc;
    stats[j] = 0.f;
    stats[256 + j] = 0.f;
}

// ------------------------------------------------- CSR aggregate, wave-per-node
// BN=false (layer 0): inputs y are raw embeddings.
// BN=true: h = relu(fmaf(y, scale, shift)) applied on the fly (fuses bn_relu).
// out[n] = h[n] + sum_t relu(h[srcs[t]] + ea_s[t]).
template <bool BN>
__global__ __launch_bounds__(256) void agg_k(
    const short* __restrict__ y, const short* __restrict__ ea_s,
    const int* __restrict__ srcs, const int* __restrict__ row_ptr,
    const float* __restrict__ ss, short* __restrict__ out,
    float* __restrict__ stats) {
    if (!BN && blockIdx.x == 0) {
        stats[threadIdx.x] = 0.f;
        stats[threadIdx.x + 256] = 0.f;
    }
    int lane = threadIdx.x & 63, wv = threadIdx.x >> 6;
    int c = lane * 4;
    float sc0 = 1.f, sc1 = 1.f, sc2 = 1.f, sc3 = 1.f;
    float sh0 = 0.f, sh1 = 0.f, sh2 = 0.f, sh3 = 0.f;
    if (BN) {
        float4 scv = *reinterpret_cast<const float4*>(ss + c);
        float4 shv = *reinterpret_cast<const float4*>(ss + 256 + c);
        sc0 = scv.x; sc1 = scv.y; sc2 = scv.z; sc3 = scv.w;
        sh0 = shv.x; sh1 = shv.y; sh2 = shv.z; sh3 = shv.w;
    }
#define HVAL(v, i) (BN ? fmaxf(fmaf(b2f(v[i]), sc##i, sh##i), 0.f) : b2f(v[i]))
    int n = blockIdx.x * 4 + wv;          // grid exact: 12500*4 = 50000
    int beg = row_ptr[n], end = row_ptr[n + 1];
    u16x4 h4 = *reinterpret_cast<const u16x4*>(y + (size_t)n * HID + c);
    float a0 = HVAL(h4, 0), a1 = HVAL(h4, 1), a2 = HVAL(h4, 2), a3 = HVAL(h4, 3);

    for (int t = beg; t < end; t += 8) {
        int m = min(8, end - t);
        int ssrc[8];
        u16x4 ev[8], gv[8];
#pragma unroll
        for (int k = 0; k < 8; ++k)
            if (k < m) ssrc[k] = srcs[t + k];
#pragma unroll
        for (int k = 0; k < 8; ++k)
            if (k < m) {
                ev[k] = *reinterpret_cast<const u16x4*>(ea_s + (size_t)(t + k) * HID + c);
                gv[k] = *reinterpret_cast<const u16x4*>(y + (size_t)ssrc[k] * HID + c);
            }
#pragma unroll
        for (int k = 0; k < 8; ++k)
            if (k < m) {
                a0 += fmaxf(b2f(ev[k][0]) + HVAL(gv[k], 0), 0.f);
                a1 += fmaxf(b2f(ev[k][1]) + HVAL(gv[k], 1), 0.f);
                a2 += fmaxf(b2f(ev[k][2]) + HVAL(gv[k], 2), 0.f);
                a3 += fmaxf(b2f(ev[k][3]) + HVAL(gv[k], 3), 0.f);
            }
    }
#undef HVAL
    u16x4 o;
    o[0] = (unsigned short)f2b(a0);
    o[1] = (unsigned short)f2b(a1);
    o[2] = (unsigned short)f2b(a2);
    o[3] = (unsigned short)f2b(a3);
    *reinterpret_cast<u16x4*>(out + (size_t)n * HID + c) = o;
}

// ----------------------------------------------------------- bf16 MFMA GEMM
// C[M,256] = act(A@W + bias). BM=256 (4 waves x 64 rows), BN=64, K=256.
// XCD-chunked swizzle; B panel (32KB) in LDS (XOR swizzle); depth-1 A
// prefetch; LDS-transposed coalesced epilogue; optional fused BN stats.
template <bool RELU, bool STATS>
__global__ __launch_bounds__(256, 3) void gemm_k(const short* __restrict__ A,
                                                 const short* __restrict__ wT,
                                                 const float* __restrict__ bias,
                                                 short* __restrict__ C,
                                                 float* __restrict__ stats, int M) {
    __shared__ short Bs[64 * 256]; // 32KB
    char* BsB = (char*)Bs;
    int wv = threadIdx.x >> 6, lane = threadIdx.x & 63;
    int lr = lane & 15, lg = lane >> 4;

    // XCD-chunked swizzle (grid 784 = 8 * 98)
    int bid = blockIdx.x;
    int sw = (bid & 7) * (gridDim.x >> 3) + (bid >> 3);
    int c0 = (sw & 3) * 64;
    int r0 = (sw >> 2) * 256 + wv * 64;

    const char* panel = (const char*)(wT + (size_t)c0 * 256);
    {
        float4 v[4];
#pragma unroll
        for (int it = 0; it < 4; ++it)
            v[it] = *reinterpret_cast<const float4*>(panel + (threadIdx.x + it * 256) * 16);
#pragma unroll
        for (int it = 0; it < 4; ++it) {
            int o = (threadIdx.x + it * 256) * 16;
            int n = o >> 9;
            *reinterpret_cast<float4*>(BsB + (o ^ ((n & 7) << 4))) = v[it];
        }
        float4 v2[4];
#pragma unroll
        for (int it = 4; it < 8; ++it)
            v2[it - 4] = *reinterpret_cast<const float4*>(panel + (threadIdx.x + it * 256) * 16);
#pragma unroll
        for (int it = 4; it < 8; ++it) {
            int o = (threadIdx.x + it * 256) * 16;
            int n = o >> 9;
            *reinterpret_cast<float4*>(BsB + (o ^ ((n & 7) << 4))) = v2[it - 4];
        }
    }

    const short* pA[4];
    bool gok[4];
#pragma unroll
    for (int f = 0; f < 4; ++f) {
        int r = r0 + f * 16 + lr;
        gok[f] = r < M;
        pA[f] = A + (size_t)r * 256 + lg * 8;
    }

    f32x4 acc[4][4] = {};
    bf16x8 aCur[4] = {}, aNxt[4] = {};
#pragma unroll
    for (int f = 0; f < 4; ++f)
        if (gok[f]) aCur[f] = *reinterpret_cast<const bf16x8*>(pA[f]);

    __syncthreads();

    for (int k0 = 0; k0 < 256; k0 += 32) {
        if (k0 < 224) {
#pragma unroll
            for (int f = 0; f < 4; ++f)
                if (gok[f]) aNxt[f] = *reinterpret_cast<const bf16x8*>(pA[f] + k0 + 32);
        }
#pragma unroll
        for (int cc = 0; cc < 4; ++cc) {
            int n = cc * 16 + lr;
            int kb = k0 * 2 + lg * 16;
            bf16x8 b = *reinterpret_cast<const bf16x8*>(
                BsB + ((n * 512 + (kb ^ ((n & 7) << 4)))));
#pragma unroll
            for (int f = 0; f < 4; ++f)
                acc[f][cc] = __builtin_amdgcn_mfma_f32_16x16x32_bf16(aCur[f], b, acc[f][cc], 0, 0, 0);
        }
#pragma unroll
        for (int f = 0; f < 4; ++f) aCur[f] = aNxt[f];
    }

    __syncthreads();
    char* S = BsB + wv * 8192;
#pragma unroll
    for (int cc = 0; cc < 4; ++cc) {
        int colL = cc * 16 + lr;
        float bi = bias[c0 + colL];
        float s = 0.f, ss2 = 0.f;
#pragma unroll
        for (int f = 0; f < 4; ++f)
#pragma unroll
            for (int i = 0; i < 4; ++i) {
                int rowL = f * 16 + lg * 4 + i;
                float v = acc[f][cc][i] + bi;
                if (RELU) v = fmaxf(v, 0.f);
                if (STATS && (r0 + rowL) < M) { s += v; ss2 = fmaf(v, v, ss2); }
                int byte = rowL * 128 + ((colL * 2) ^ ((rowL & 7) << 4));
                *reinterpret_cast<short*>(S + byte) = f2b(v);
            }
        if (STATS) {
            s   += __shfl_xor(s, 16);  ss2 += __shfl_xor(ss2, 16);
            s   += __shfl_xor(s, 32);  ss2 += __shfl_xor(ss2, 32);
            if (lg == 0) {
                atomicAdd(&stats[c0 + colL], s);
                atomicAdd(&stats[HID + c0 + colL], ss2);
            }
        }
    }
    asm volatile("s_waitcnt lgkmcnt(0)" ::: "memory");
#pragma unroll
    for (int j = 0; j < 8; ++j) {
        int rowL = j * 8 + (lane >> 3);
        int cb = (lane & 7) * 16;
        int byte = rowL * 128 + (cb ^ ((rowL & 7) << 4));
        int4 d = *reinterpret_cast<const int4*>(S + byte);
        int grow = r0 + rowL;
        if (grow < M)
            *reinterpret_cast<int4*>((char*)C + (size_t)grow * 512 + c0 * 2 + cb) = d;
    }
}

// ------------------------------------------------------------------ pool
// Applies the final layer's BN+relu on the fly (reads pre-BN z + scale/shift).
#define PNB 64
__global__ void pool_k(const short* __restrict__ y, const int* __restrict__ batch,
                       const float* __restrict__ ss, float* __restrict__ g) {
    int j = threadIdx.x;
    float sc = ss[j], sh = ss[256 + j];
    int n0 = blockIdx.x * PNB;
    int n1 = min(n0 + PNB, NNODES);
    int cur = batch[n0];
    float acc = 0.f;
    for (int n = n0; n < n1; ++n) {
        int b = batch[n];
        if (b != cur) {
            atomicAdd(&g[(size_t)cur * HID + j], acc);
            acc = 0.f; cur = b;
        }
        float z = b2f((unsigned short)y[(size_t)n * HID + j]);
        acc += fmaxf(fmaf(z, sc, sh), 0.f);
    }
    atomicAdd(&g[(size_t)cur * HID + j], acc);
}

// ------------------------------------------------------------------ head
__global__ void head_k(const float* __restrict__ g, const float* __restrict__ w1,
                       const float* __restrict__ b1, const float* __restrict__ w2,
                       const float* __restrict__ b2, float* __restrict__ out) {
    int gi = blockIdx.x;
    int j  = threadIdx.x;
    __shared__ float gr[256];
    __shared__ float hid[128];
    gr[j]       = g[gi * 256 + j];
    gr[j + 128] = g[gi * 256 + 128 + j];
    __syncthreads();
    float acc = b1[j];
    for (int k = 0; k < 256; ++k) acc = fmaf(gr[k], w1[k * 128 + j], acc);
    hid[j] = fmaxf(acc, 0.f);
    __syncthreads();
    if (j < 12) {
        float o = b2[j];
#pragma unroll
        for (int k = 0; k < 128; ++k) o = fmaf(hid[k], w2[k * 12 + j], o);
        out[gi * 12 + j] = o;
    }
}

// ---------------------------------------------------------------- launch
extern "C" void kernel_launch(void* const* d_in, const int* in_sizes, int n_in,
                              void* d_out, int out_size, void* d_ws, size_t ws_size,
                              hipStream_t stream) {
    const float* x     = (const float*)d_in[0];
    const int*   ei    = (const int*)d_in[1];
    const int*   batch = (const int*)d_in[2];
    const float* eattr = (const float*)d_in[3];
    const float* nw    = (const float*)d_in[4];
    const float* nb    = (const float*)d_in[5];
    const float* ew    = (const float*)d_in[6];
    const float* eb    = (const float*)d_in[7];
    const float* w1    = (const float*)d_in[8];
    const float* b1    = (const float*)d_in[9];
    const float* w2    = (const float*)d_in[10];
    const float* b2    = (const float*)d_in[11];
    const float* gam   = (const float*)d_in[12];
    const float* bet   = (const float*)d_in[13];
    const float* hw1   = (const float*)d_in[14];
    const float* hb1   = (const float*)d_in[15];
    const float* hw2   = (const float*)d_in[16];
    const float* hb2   = (const float*)d_in[17];
    float* out = (float*)d_out;

    const size_t NH = (size_t)NNODES * HID;
    const size_t EH = (size_t)NEDGES * HID;
    size_t off = 0;
    char* base = (char*)d_ws;
    auto alloc = [&](size_t bytes) -> void* {
        void* p = base + off;
        off += (bytes + 255) & ~(size_t)255;
        return p;
    };
    short* y       = (short*)alloc(NH * 2);   // embed / gemm2 out (pre-BN z)
    short* a       = (short*)alloc(NH * 2);   // agg out
    short* bbuf    = (short*)alloc(NH * 2);   // gemm1 out
    short* wT      = (short*)alloc(8 * 65536 * 2);
    short* ea_s    = (short*)alloc(EH * 2);       // 153.6 MB, layer-invariant
    float* eattr_s = (float*)alloc((size_t)NEDGES * 16 * 4); // 19.2 MB slot-ordered
    int*   srcs    = (int*)alloc((size_t)NEDGES * 4);
    float* stats   = (float*)alloc(512 * 4);
    float* ssbuf   = (float*)alloc(512 * 4);  // (scale, shift)
    float* g       = (float*)alloc((size_t)NGRAPHS * HID * 4);
    int*   deg     = (int*)alloc((size_t)NNODES * 4);
    int*   partial = (int*)alloc((size_t)NNODES * 4);
    int*   btot    = (int*)alloc(256 * 4);
    int*   row_ptr = (int*)alloc((size_t)(NNODES + 1) * 4);
    int*   cursor  = (int*)alloc((size_t)NNODES * 4);
    int*   slot    = (int*)alloc((size_t)NEDGES * 4);

    wconv_k<<<dim3(256, 4), 256, 0, stream>>>(w1, wT);
    wconv_k<<<dim3(256, 4), 256, 0, stream>>>(w2, wT + 4 * 65536);
    node_embed_k<<<NNODES, 256, 0, stream>>>(x, nw, nb, y);

    hipMemsetAsync(deg, 0, (size_t)NNODES * 4, stream);
    deg_k<<<(NEDGES + 255) / 256, 256, 0, stream>>>(ei, deg);
    const int NB = (NNODES + 255) / 256;
    scan1_k<<<NB, 256, 0, stream>>>(deg, partial, btot);
    scan2_k<<<1, 256, 0, stream>>>(btot, NB);
    scan3_k<<<NB, 256, 0, stream>>>(deg, partial, btot, row_ptr, cursor);
    fill_k<<<(NEDGES + 255) / 256, 256, 0, stream>>>(ei, cursor, slot, srcs);
    esort3_k<<<(NEDGES + 63) / 64, 256, 0, stream>>>(eattr, slot, eattr_s);
    ea_k<<<(NEDGES + 4 * EA_EPW - 1) / (4 * EA_EPW), 256, 0, stream>>>(
        eattr_s, ew, eb, ea_s);

    const int GG = ((NNODES + 255) / 256) * 4;   // 784, %8==0
    for (int l = 0; l < L; ++l) {
        if (l == 0) {
            agg_k<false><<<NNODES / 4, 256, 0, stream>>>(
                y, ea_s, srcs, row_ptr, nullptr, a, stats);
        } else {
            bnprep_k<<<1, 256, 0, stream>>>(stats, gam + (l - 1) * HID,
                                            bet + (l - 1) * HID, ssbuf);
            agg_k<true><<<NNODES / 4, 256, 0, stream>>>(
                y, ea_s, srcs, row_ptr, ssbuf, a, stats);
        }
        gemm_k<true, false><<<GG, 256, 0, stream>>>(
            a, wT + (size_t)l * 65536, b1 + l * HID, bbuf, nullptr, NNODES);
        gemm_k<false, true><<<GG, 256, 0, stream>>>(
            bbuf, wT + (size_t)(4 + l) * 65536, b2 + l * HID, y, stats, NNODES);
    }

    bnprep_k<<<1, 256, 0, stream>>>(stats, gam + 3 * HID, bet + 3 * HID, ssbuf);
    hipMemsetAsync(g, 0, (size_t)NGRAPHS * HID * 4, stream);
    pool_k<<<(NNODES + PNB - 1) / PNB, 256, 0, stream>>>(y, batch, ssbuf, g);
    head_k<<<NGRAPHS, 128, 0, stream>>>(g, hw1, hb1, hw2, hb2, out);
}

// Round 13
// 748.121 us; speedup vs baseline: 1.2532x; 1.0316x over previous
//
#include <hip/hip_runtime.h>
#include <hip/hip_bf16.h>

#define HID     256
#define NNODES  50000
#define NEDGES  300000
#define NGRAPHS 128
#define L       4

typedef __attribute__((ext_vector_type(8))) short bf16x8;
typedef __attribute__((ext_vector_type(4))) float f32x4;
typedef __attribute__((ext_vector_type(4))) unsigned short u16x4;

static __device__ __forceinline__ float b2f(unsigned short s) {
    union { unsigned u; float f; } v;
    v.u = ((unsigned)s) << 16;
    return v.f;
}
static __device__ __forceinline__ short f2b(float f) {
    __hip_bfloat16 h = __float2bfloat16(f);
    return *reinterpret_cast<short*>(&h);
}

#define FMA4(mm, s, wv4) do { \
    mm.x = fmaf((s), (wv4).x, mm.x); \
    mm.y = fmaf((s), (wv4).y, mm.y); \
    mm.z = fmaf((s), (wv4).z, mm.z); \
    mm.w = fmaf((s), (wv4).w, mm.w); } while (0)

// ------------------------------------------------ weight convert + transpose
__global__ void wconv_k(const float* __restrict__ w, short* __restrict__ wT) {
    int m = blockIdx.y, n = blockIdx.x, k = threadIdx.x;
    wT[(size_t)m * 65536 + n * 256 + k] = f2b(w[(size_t)m * 65536 + k * 256 + n]);
}

// ---------------------------------------------------------------- node embed
// Wave owns 4 columns (c..c+3); lane holds w[0..31][c..c+3] in regs
// (launch_bounds(256,2) so they stay register-resident); 16 nodes per wave.
// Replaces block-per-node version whose 50000 blocks re-read node_w from L2
// (~1.6 GB) at 420 GB/s effective.
#define NE_NPW 16
__global__ __launch_bounds__(256, 2) void node_embed_k(
    const float* __restrict__ x, const float* __restrict__ w,
    const float* __restrict__ b, short* __restrict__ hb) {
    int lane = threadIdx.x & 63, wv = threadIdx.x >> 6;
    int c = lane * 4;
    float4 wr[32];
#pragma unroll
    for (int k = 0; k < 32; ++k)
        wr[k] = *reinterpret_cast<const float4*>(w + k * HID + c);
    float4 bb = *reinterpret_cast<const float4*>(b + c);

    int n0 = (blockIdx.x * 4 + wv) * NE_NPW;
    int n1 = min(n0 + NE_NPW, NNODES);
    for (int n = n0; n < n1; ++n) {
        const float4* xp = reinterpret_cast<const float4*>(x + (size_t)n * 32);
        float4 x0 = xp[0], x1 = xp[1], x2 = xp[2], x3 = xp[3];
        float4 x4 = xp[4], x5 = xp[5], x6 = xp[6], x7 = xp[7];
        float4 m = bb;
        FMA4(m, x0.x, wr[0]);  FMA4(m, x0.y, wr[1]);
        FMA4(m, x0.z, wr[2]);  FMA4(m, x0.w, wr[3]);
        FMA4(m, x1.x, wr[4]);  FMA4(m, x1.y, wr[5]);
        FMA4(m, x1.z, wr[6]);  FMA4(m, x1.w, wr[7]);
        FMA4(m, x2.x, wr[8]);  FMA4(m, x2.y, wr[9]);
        FMA4(m, x2.z, wr[10]); FMA4(m, x2.w, wr[11]);
        FMA4(m, x3.x, wr[12]); FMA4(m, x3.y, wr[13]);
        FMA4(m, x3.z, wr[14]); FMA4(m, x3.w, wr[15]);
        FMA4(m, x4.x, wr[16]); FMA4(m, x4.y, wr[17]);
        FMA4(m, x4.z, wr[18]); FMA4(m, x4.w, wr[19]);
        FMA4(m, x5.x, wr[20]); FMA4(m, x5.y, wr[21]);
        FMA4(m, x5.z, wr[22]); FMA4(m, x5.w, wr[23]);
        FMA4(m, x6.x, wr[24]); FMA4(m, x6.y, wr[25]);
        FMA4(m, x6.z, wr[26]); FMA4(m, x6.w, wr[27]);
        FMA4(m, x7.x, wr[28]); FMA4(m, x7.y, wr[29]);
        FMA4(m, x7.z, wr[30]); FMA4(m, x7.w, wr[31]);
        u16x4 o;
        o[0] = (unsigned short)f2b(m.x);
        o[1] = (unsigned short)f2b(m.y);
        o[2] = (unsigned short)f2b(m.z);
        o[3] = (unsigned short)f2b(m.w);
        *reinterpret_cast<u16x4*>(hb + (size_t)n * HID + c) = o;
    }
}

// ------------------------------------------------------------- CSR building
__global__ void deg_k(const int* __restrict__ ei, int* __restrict__ deg) {
    int e = blockIdx.x * 256 + threadIdx.x;
    if (e < NEDGES) atomicAdd(&deg[ei[NEDGES + e]], 1);
}

__global__ void scan1_k(const int* __restrict__ deg, int* __restrict__ partial,
                        int* __restrict__ btot) {
    __shared__ int s[256];
    int t = threadIdx.x;
    int gi = blockIdx.x * 256 + t;
    s[t] = (gi < NNODES) ? deg[gi] : 0;
    __syncthreads();
    for (int off = 1; off < 256; off <<= 1) {
        int u = (t >= off) ? s[t - off] : 0;
        __syncthreads();
        s[t] += u;
        __syncthreads();
    }
    if (gi < NNODES) partial[gi] = s[t];
    if (t == 255) btot[blockIdx.x] = s[255];
}

__global__ void scan2_k(int* __restrict__ btot, int nb) {
    __shared__ int s[256];
    int t = threadIdx.x;
    s[t] = (t < nb) ? btot[t] : 0;
    __syncthreads();
    for (int off = 1; off < 256; off <<= 1) {
        int u = (t >= off) ? s[t - off] : 0;
        __syncthreads();
        s[t] += u;
        __syncthreads();
    }
    btot[t] = s[t];
}

__global__ void scan3_k(const int* __restrict__ deg, const int* __restrict__ partial,
                        const int* __restrict__ btot, int* __restrict__ row_ptr,
                        int* __restrict__ cursor) {
    int gi = blockIdx.x * 256 + threadIdx.x;
    if (gi >= NNODES) return;
    int b = blockIdx.x;
    int incl = partial[gi] + (b ? btot[b - 1] : 0);
    int start = incl - deg[gi];
    row_ptr[gi] = start;
    cursor[gi] = start;
    if (gi == NNODES - 1) row_ptr[NNODES] = incl;
}

// fill: slot[e] = CSR position of edge e; srcs[pos] = src node (scatter).
__global__ void fill_k(const int* __restrict__ ei, int* __restrict__ cursor,
                       int* __restrict__ slot, int* __restrict__ srcs) {
    int e = blockIdx.x * 256 + threadIdx.x;
    if (e < NEDGES) {
        int d = ei[NEDGES + e];
        int pos = atomicAdd(&cursor[d], 1);
        slot[e] = pos;
        srcs[pos] = ei[e];
    }
}

// ---------- scatter the SMALL payload: eattr_s[slot[e]] = eattr[e] (fp32 64B)
__global__ void esort3_k(const float* __restrict__ eattr, const int* __restrict__ slot,
                         float* __restrict__ eattr_s) {
    int e = blockIdx.x * 64 + (threadIdx.x >> 2);   // 64 edges per block
    int q = threadIdx.x & 3;                        // 4 lanes per edge (16B each)
    if (e < NEDGES) {
        float4 v = reinterpret_cast<const float4*>(eattr + (size_t)e * 16)[q];
        reinterpret_cast<float4*>(eattr_s + (size_t)slot[e] * 16)[q] = v;
    }
}

// ---------------- one-time: ea_s[t] = bf16(eattr_s[t] @ ew + eb)
// Both sides streaming. 16 edges per wave (4 groups of 4).
#define EA_EPW 16
__global__ __launch_bounds__(256) void ea_k(const float* __restrict__ eattr_s,
                                            const float* __restrict__ ew,
                                            const float* __restrict__ ebias,
                                            short* __restrict__ ea_s) {
    int lane = threadIdx.x & 63, wv = threadIdx.x >> 6;
    int c = lane * 4;
    float4 w0  = *reinterpret_cast<const float4*>(ew + 0 * 256 + c);
    float4 w1  = *reinterpret_cast<const float4*>(ew + 1 * 256 + c);
    float4 w2  = *reinterpret_cast<const float4*>(ew + 2 * 256 + c);
    float4 w3  = *reinterpret_cast<const float4*>(ew + 3 * 256 + c);
    float4 w4  = *reinterpret_cast<const float4*>(ew + 4 * 256 + c);
    float4 w5  = *reinterpret_cast<const float4*>(ew + 5 * 256 + c);
    float4 w6  = *reinterpret_cast<const float4*>(ew + 6 * 256 + c);
    float4 w7  = *reinterpret_cast<const float4*>(ew + 7 * 256 + c);
    float4 w8  = *reinterpret_cast<const float4*>(ew + 8 * 256 + c);
    float4 w9  = *reinterpret_cast<const float4*>(ew + 9 * 256 + c);
    float4 w10 = *reinterpret_cast<const float4*>(ew + 10 * 256 + c);
    float4 w11 = *reinterpret_cast<const float4*>(ew + 11 * 256 + c);
    float4 w12 = *reinterpret_cast<const float4*>(ew + 12 * 256 + c);
    float4 w13 = *reinterpret_cast<const float4*>(ew + 13 * 256 + c);
    float4 w14 = *reinterpret_cast<const float4*>(ew + 14 * 256 + c);
    float4 w15 = *reinterpret_cast<const float4*>(ew + 15 * 256 + c);
    float4 ebv = *reinterpret_cast<const float4*>(ebias + c);

    int tw = (blockIdx.x * 4 + wv) * EA_EPW;
    for (int t0 = tw; t0 < min(tw + EA_EPW, NEDGES); t0 += 4) {
        float4 q[4][4];
#pragma unroll
        for (int j = 0; j < 4; ++j) {
            const float4* ep = reinterpret_cast<const float4*>(eattr_s + (size_t)(t0 + j) * 16);
            q[j][0] = ep[0]; q[j][1] = ep[1]; q[j][2] = ep[2]; q[j][3] = ep[3];
        }
#pragma unroll
        for (int j = 0; j < 4; ++j) {
            float4 m = ebv;
            FMA4(m, q[j][0].x, w0);  FMA4(m, q[j][0].y, w1);
            FMA4(m, q[j][0].z, w2);  FMA4(m, q[j][0].w, w3);
            FMA4(m, q[j][1].x, w4);  FMA4(m, q[j][1].y, w5);
            FMA4(m, q[j][1].z, w6);  FMA4(m, q[j][1].w, w7);
            FMA4(m, q[j][2].x, w8);  FMA4(m, q[j][2].y, w9);
            FMA4(m, q[j][2].z, w10); FMA4(m, q[j][2].w, w11);
            FMA4(m, q[j][3].x, w12); FMA4(m, q[j][3].y, w13);
            FMA4(m, q[j][3].z, w14); FMA4(m, q[j][3].w, w15);
            u16x4 o;
            o[0] = (unsigned short)f2b(m.x);
            o[1] = (unsigned short)f2b(m.y);
            o[2] = (unsigned short)f2b(m.z);
            o[3] = (unsigned short)f2b(m.w);
            *reinterpret_cast<u16x4*>(ea_s + (size_t)(t0 + j) * HID + c) = o;
        }
    }
}

// --------------- BN prep: stats -> per-channel (scale, shift), re-zero stats
__global__ void bnprep_k(float* __restrict__ stats, const float* __restrict__ gamma,
                         const float* __restrict__ beta, float* __restrict__ ss) {
    int j = threadIdx.x;
    float mu  = stats[j] * (1.f / NNODES);
    float var = stats[256 + j] * (1.f / NNODES) - mu * mu;
    float sc  = rsqrtf(var + 1e-5f) * gamma[j];
    ss[j]       = sc;
    ss[256 + j] = beta[j] - mu * sc;
    stats[j] = 0.f;
    stats[256 + j] = 0.f;
}

// ------------------------------------------------- CSR aggregate, wave-per-node
// BN=false (layer 0): inputs y are raw embeddings.
// BN=true: h = relu(fmaf(y, scale, shift)) applied on the fly (fuses bn_relu).
// out[n] = h[n] + sum_t relu(h[srcs[t]] + ea_s[t]).
template <bool BN>
__global__ __launch_bounds__(256) void agg_k(
    const short* __restrict__ y, const short* __restrict__ ea_s,
    const int* __restrict__ srcs, const int* __restrict__ row_ptr,
    const float* __restrict__ ss, short* __restrict__ out,
    float* __restrict__ stats) {
    if (!BN && blockIdx.x == 0) {
        stats[threadIdx.x] = 0.f;
        stats[threadIdx.x + 256] = 0.f;
    }
    int lane = threadIdx.x & 63, wv = threadIdx.x >> 6;
    int c = lane * 4;
    float sc0 = 1.f, sc1 = 1.f, sc2 = 1.f, sc3 = 1.f;
    float sh0 = 0.f, sh1 = 0.f, sh2 = 0.f, sh3 = 0.f;
    if (BN) {
        float4 scv = *reinterpret_cast<const float4*>(ss + c);
        float4 shv = *reinterpret_cast<const float4*>(ss + 256 + c);
        sc0 = scv.x; sc1 = scv.y; sc2 = scv.z; sc3 = scv.w;
        sh0 = shv.x; sh1 = shv.y; sh2 = shv.z; sh3 = shv.w;
    }
#define HVAL(v, i) (BN ? fmaxf(fmaf(b2f(v[i]), sc##i, sh##i), 0.f) : b2f(v[i]))
    int n = blockIdx.x * 4 + wv;          // grid exact: 12500*4 = 50000
    int beg = row_ptr[n], end = row_ptr[n + 1];
    u16x4 h4 = *reinterpret_cast<const u16x4*>(y + (size_t)n * HID + c);
    float a0 = HVAL(h4, 0), a1 = HVAL(h4, 1), a2 = HVAL(h4, 2), a3 = HVAL(h4, 3);

    for (int t = beg; t < end; t += 8) {
        int m = min(8, end - t);
        int ssrc[8];
        u16x4 ev[8], gv[8];
#pragma unroll
        for (int k = 0; k < 8; ++k)
            if (k < m) ssrc[k] = srcs[t + k];
#pragma unroll
        for (int k = 0; k < 8; ++k)
            if (k < m) {
                ev[k] = *reinterpret_cast<const u16x4*>(ea_s + (size_t)(t + k) * HID + c);
                gv[k] = *reinterpret_cast<const u16x4*>(y + (size_t)ssrc[k] * HID + c);
            }
#pragma unroll
        for (int k = 0; k < 8; ++k)
            if (k < m) {
                a0 += fmaxf(b2f(ev[k][0]) + HVAL(gv[k], 0), 0.f);
                a1 += fmaxf(b2f(ev[k][1]) + HVAL(gv[k], 1), 0.f);
                a2 += fmaxf(b2f(ev[k][2]) + HVAL(gv[k], 2), 0.f);
                a3 += fmaxf(b2f(ev[k][3]) + HVAL(gv[k], 3), 0.f);
            }
    }
#undef HVAL
    u16x4 o;
    o[0] = (unsigned short)f2b(a0);
    o[1] = (unsigned short)f2b(a1);
    o[2] = (unsigned short)f2b(a2);
    o[3] = (unsigned short)f2b(a3);
    *reinterpret_cast<u16x4*>(out + (size_t)n * HID + c) = o;
}

// ----------------------------------------------------------- bf16 MFMA GEMM
// C[M,256] = act(A@W + bias). BM=256 (4 waves x 64 rows), BN=64, K=256.
// XCD-chunked swizzle; B panel (32KB) in LDS (XOR swizzle); depth-1 A
// prefetch; LDS-transposed coalesced epilogue; optional fused BN stats.
template <bool RELU, bool STATS>
__global__ __launch_bounds__(256, 3) void gemm_k(const short* __restrict__ A,
                                                 const short* __restrict__ wT,
                                                 const float* __restrict__ bias,
                                                 short* __restrict__ C,
                                                 float* __restrict__ stats, int M) {
    __shared__ short Bs[64 * 256]; // 32KB
    char* BsB = (char*)Bs;
    int wv = threadIdx.x >> 6, lane = threadIdx.x & 63;
    int lr = lane & 15, lg = lane >> 4;

    // XCD-chunked swizzle (grid 784 = 8 * 98)
    int bid = blockIdx.x;
    int sw = (bid & 7) * (gridDim.x >> 3) + (bid >> 3);
    int c0 = (sw & 3) * 64;
    int r0 = (sw >> 2) * 256 + wv * 64;

    const char* panel = (const char*)(wT + (size_t)c0 * 256);
    {
        float4 v[4];
#pragma unroll
        for (int it = 0; it < 4; ++it)
            v[it] = *reinterpret_cast<const float4*>(panel + (threadIdx.x + it * 256) * 16);
#pragma unroll
        for (int it = 0; it < 4; ++it) {
            int o = (threadIdx.x + it * 256) * 16;
            int n = o >> 9;
            *reinterpret_cast<float4*>(BsB + (o ^ ((n & 7) << 4))) = v[it];
        }
        float4 v2[4];
#pragma unroll
        for (int it = 4; it < 8; ++it)
            v2[it - 4] = *reinterpret_cast<const float4*>(panel + (threadIdx.x + it * 256) * 16);
#pragma unroll
        for (int it = 4; it < 8; ++it) {
            int o = (threadIdx.x + it * 256) * 16;
            int n = o >> 9;
            *reinterpret_cast<float4*>(BsB + (o ^ ((n & 7) << 4))) = v2[it - 4];
        }
    }

    const short* pA[4];
    bool gok[4];
#pragma unroll
    for (int f = 0; f < 4; ++f) {
        int r = r0 + f * 16 + lr;
        gok[f] = r < M;
        pA[f] = A + (size_t)r * 256 + lg * 8;
    }

    f32x4 acc[4][4] = {};
    bf16x8 aCur[4] = {}, aNxt[4] = {};
#pragma unroll
    for (int f = 0; f < 4; ++f)
        if (gok[f]) aCur[f] = *reinterpret_cast<const bf16x8*>(pA[f]);

    __syncthreads();

    for (int k0 = 0; k0 < 256; k0 += 32) {
        if (k0 < 224) {
#pragma unroll
            for (int f = 0; f < 4; ++f)
                if (gok[f]) aNxt[f] = *reinterpret_cast<const bf16x8*>(pA[f] + k0 + 32);
        }
#pragma unroll
        for (int cc = 0; cc < 4; ++cc) {
            int n = cc * 16 + lr;
            int kb = k0 * 2 + lg * 16;
            bf16x8 b = *reinterpret_cast<const bf16x8*>(
                BsB + ((n * 512 + (kb ^ ((n & 7) << 4)))));
#pragma unroll
            for (int f = 0; f < 4; ++f)
                acc[f][cc] = __builtin_amdgcn_mfma_f32_16x16x32_bf16(aCur[f], b, acc[f][cc], 0, 0, 0);
        }
#pragma unroll
        for (int f = 0; f < 4; ++f) aCur[f] = aNxt[f];
    }

    __syncthreads();
    char* S = BsB + wv * 8192;
#pragma unroll
    for (int cc = 0; cc < 4; ++cc) {
        int colL = cc * 16 + lr;
        float bi = bias[c0 + colL];
        float s = 0.f, ss2 = 0.f;
#pragma unroll
        for (int f = 0; f < 4; ++f)
#pragma unroll
            for (int i = 0; i < 4; ++i) {
                int rowL = f * 16 + lg * 4 + i;
                float v = acc[f][cc][i] + bi;
                if (RELU) v = fmaxf(v, 0.f);
                if (STATS && (r0 + rowL) < M) { s += v; ss2 = fmaf(v, v, ss2); }
                int byte = rowL * 128 + ((colL * 2) ^ ((rowL & 7) << 4));
                *reinterpret_cast<short*>(S + byte) = f2b(v);
            }
        if (STATS) {
            s   += __shfl_xor(s, 16);  ss2 += __shfl_xor(ss2, 16);
            s   += __shfl_xor(s, 32);  ss2 += __shfl_xor(ss2, 32);
            if (lg == 0) {
                atomicAdd(&stats[c0 + colL], s);
                atomicAdd(&stats[HID + c0 + colL], ss2);
            }
        }
    }
    asm volatile("s_waitcnt lgkmcnt(0)" ::: "memory");
#pragma unroll
    for (int j = 0; j < 8; ++j) {
        int rowL = j * 8 + (lane >> 3);
        int cb = (lane & 7) * 16;
        int byte = rowL * 128 + (cb ^ ((rowL & 7) << 4));
        int4 d = *reinterpret_cast<const int4*>(S + byte);
        int grow = r0 + rowL;
        if (grow < M)
            *reinterpret_cast<int4*>((char*)C + (size_t)grow * 512 + c0 * 2 + cb) = d;
    }
}

// ------------------------------------------------------------------ pool
// Applies the final layer's BN+relu on the fly (reads pre-BN z + scale/shift).
#define PNB 64
__global__ void pool_k(const short* __restrict__ y, const int* __restrict__ batch,
                       const float* __restrict__ ss, float* __restrict__ g) {
    int j = threadIdx.x;
    float sc = ss[j], sh = ss[256 + j];
    int n0 = blockIdx.x * PNB;
    int n1 = min(n0 + PNB, NNODES);
    int cur = batch[n0];
    float acc = 0.f;
    for (int n = n0; n < n1; ++n) {
        int b = batch[n];
        if (b != cur) {
            atomicAdd(&g[(size_t)cur * HID + j], acc);
            acc = 0.f; cur = b;
        }
        float z = b2f((unsigned short)y[(size_t)n * HID + j]);
        acc += fmaxf(fmaf(z, sc, sh), 0.f);
    }
    atomicAdd(&g[(size_t)cur * HID + j], acc);
}

// ------------------------------------------------------------------ head
__global__ void head_k(const float* __restrict__ g, const float* __restrict__ w1,
                       const float* __restrict__ b1, const float* __restrict__ w2,
                       const float* __restrict__ b2, float* __restrict__ out) {
    int gi = blockIdx.x;
    int j  = threadIdx.x;
    __shared__ float gr[256];
    __shared__ float hid[128];
    gr[j]       = g[gi * 256 + j];
    gr[j + 128] = g[gi * 256 + 128 + j];
    __syncthreads();
    float acc = b1[j];
    for (int k = 0; k < 256; ++k) acc = fmaf(gr[k], w1[k * 128 + j], acc);
    hid[j] = fmaxf(acc, 0.f);
    __syncthreads();
    if (j < 12) {
        float o = b2[j];
#pragma unroll
        for (int k = 0; k < 128; ++k) o = fmaf(hid[k], w2[k * 12 + j], o);
        out[gi * 12 + j] = o;
    }
}

// ---------------------------------------------------------------- launch
extern "C" void kernel_launch(void* const* d_in, const int* in_sizes, int n_in,
                              void* d_out, int out_size, void* d_ws, size_t ws_size,
                              hipStream_t stream) {
    const float* x     = (const float*)d_in[0];
    const int*   ei    = (const int*)d_in[1];
    const int*   batch = (const int*)d_in[2];
    const float* eattr = (const float*)d_in[3];
    const float* nw    = (const float*)d_in[4];
    const float* nb    = (const float*)d_in[5];
    const float* ew    = (const float*)d_in[6];
    const float* eb    = (const float*)d_in[7];
    const float* w1    = (const float*)d_in[8];
    const float* b1    = (const float*)d_in[9];
    const float* w2    = (const float*)d_in[10];
    const float* b2    = (const float*)d_in[11];
    const float* gam   = (const float*)d_in[12];
    const float* bet   = (const float*)d_in[13];
    const float* hw1   = (const float*)d_in[14];
    const float* hb1   = (const float*)d_in[15];
    const float* hw2   = (const float*)d_in[16];
    const float* hb2   = (const float*)d_in[17];
    float* out = (float*)d_out;

    const size_t NH = (size_t)NNODES * HID;
    const size_t EH = (size_t)NEDGES * HID;
    size_t off = 0;
    char* base = (char*)d_ws;
    auto alloc = [&](size_t bytes) -> void* {
        void* p = base + off;
        off += (bytes + 255) & ~(size_t)255;
        return p;
    };
    short* y       = (short*)alloc(NH * 2);   // embed / gemm2 out (pre-BN z)
    short* a       = (short*)alloc(NH * 2);   // agg out
    short* bbuf    = (short*)alloc(NH * 2);   // gemm1 out
    short* wT      = (short*)alloc(8 * 65536 * 2);
    short* ea_s    = (short*)alloc(EH * 2);       // 153.6 MB, layer-invariant
    float* eattr_s = (float*)alloc((size_t)NEDGES * 16 * 4); // 19.2 MB slot-ordered
    int*   srcs    = (int*)alloc((size_t)NEDGES * 4);
    float* stats   = (float*)alloc(512 * 4);
    float* ssbuf   = (float*)alloc(512 * 4);  // (scale, shift)
    float* g       = (float*)alloc((size_t)NGRAPHS * HID * 4);
    int*   deg     = (int*)alloc((size_t)NNODES * 4);
    int*   partial = (int*)alloc((size_t)NNODES * 4);
    int*   btot    = (int*)alloc(256 * 4);
    int*   row_ptr = (int*)alloc((size_t)(NNODES + 1) * 4);
    int*   cursor  = (int*)alloc((size_t)NNODES * 4);
    int*   slot    = (int*)alloc((size_t)NEDGES * 4);

    wconv_k<<<dim3(256, 4), 256, 0, stream>>>(w1, wT);
    wconv_k<<<dim3(256, 4), 256, 0, stream>>>(w2, wT + 4 * 65536);
    node_embed_k<<<(NNODES + 4 * NE_NPW - 1) / (4 * NE_NPW), 256, 0, stream>>>(
        x, nw, nb, y);

    hipMemsetAsync(deg, 0, (size_t)NNODES * 4, stream);
    deg_k<<<(NEDGES + 255) / 256, 256, 0, stream>>>(ei, deg);
    const int NB = (NNODES + 255) / 256;
    scan1_k<<<NB, 256, 0, stream>>>(deg, partial, btot);
    scan2_k<<<1, 256, 0, stream>>>(btot, NB);
    scan3_k<<<NB, 256, 0, stream>>>(deg, partial, btot, row_ptr, cursor);
    fill_k<<<(NEDGES + 255) / 256, 256, 0, stream>>>(ei, cursor, slot, srcs);
    esort3_k<<<(NEDGES + 63) / 64, 256, 0, stream>>>(eattr, slot, eattr_s);
    ea_k<<<(NEDGES + 4 * EA_EPW - 1) / (4 * EA_EPW), 256, 0, stream>>>(
        eattr_s, ew, eb, ea_s);

    const int GG = ((NNODES + 255) / 256) * 4;   // 784, %8==0
    for (int l = 0; l < L; ++l) {
        if (l == 0) {
            agg_k<false><<<NNODES / 4, 256, 0, stream>>>(
                y, ea_s, srcs, row_ptr, nullptr, a, stats);
        } else {
            bnprep_k<<<1, 256, 0, stream>>>(stats, gam + (l - 1) * HID,
                                            bet + (l - 1) * HID, ssbuf);
            agg_k<true><<<NNODES / 4, 256, 0, stream>>>(
                y, ea_s, srcs, row_ptr, ssbuf, a, stats);
        }
        gemm_k<true, false><<<GG, 256, 0, stream>>>(
            a, wT + (size_t)l * 65536, b1 + l * HID, bbuf, nullptr, NNODES);
        gemm_k<false, true><<<GG, 256, 0, stream>>>(
            bbuf, wT + (size_t)(4 + l) * 65536, b2 + l * HID, y, stats, NNODES);
    }

    bnprep_k<<<1, 256, 0, stream>>>(stats, gam + 3 * HID, bet + 3 * HID, ssbuf);
    hipMemsetAsync(g, 0, (size_t)NGRAPHS * HID * 4, stream);
    pool_k<<<(NNODES + PNB - 1) / PNB, 256, 0, stream>>>(y, batch, ssbuf, g);
    head_k<<<NGRAPHS, 128, 0, stream>>>(g, hw1, hb1, hw2, hb2, out);
}

// Round 15
// 743.587 us; speedup vs baseline: 1.2609x; 1.0061x over previous
//
#include <hip/hip_runtime.h>
#include <hip/hip_bf16.h>

#define HID     256
#define NNODES  50000
#define NEDGES  300000
#define NGRAPHS 128
#define L       4

typedef __attribute__((ext_vector_type(8))) short bf16x8;
typedef __attribute__((ext_vector_type(4))) float f32x4;
typedef __attribute__((ext_vector_type(4))) unsigned short u16x4;

static __device__ __forceinline__ float b2f(unsigned short s) {
    union { unsigned u; float f; } v;
    v.u = ((unsigned)s) << 16;
    return v.f;
}
static __device__ __forceinline__ short f2b(float f) {
    __hip_bfloat16 h = __float2bfloat16(f);
    return *reinterpret_cast<short*>(&h);
}

#define FMA4(mm, s, wv4) do { \
    mm.x = fmaf((s), (wv4).x, mm.x); \
    mm.y = fmaf((s), (wv4).y, mm.y); \
    mm.z = fmaf((s), (wv4).z, mm.z); \
    mm.w = fmaf((s), (wv4).w, mm.w); } while (0)

// ------------------------------------------------ weight convert + transpose
__global__ void wconv_k(const float* __restrict__ w, short* __restrict__ wT) {
    int m = blockIdx.y, n = blockIdx.x, k = threadIdx.x;
    wT[(size_t)m * 65536 + n * 256 + k] = f2b(w[(size_t)m * 65536 + k * 256 + n]);
}

// ---------------------------------------------------------------- node embed
#define NE_NPW 16
__global__ __launch_bounds__(256, 2) void node_embed_k(
    const float* __restrict__ x, const float* __restrict__ w,
    const float* __restrict__ b, short* __restrict__ hb) {
    int lane = threadIdx.x & 63, wv = threadIdx.x >> 6;
    int c = lane * 4;
    float4 wr[32];
#pragma unroll
    for (int k = 0; k < 32; ++k)
        wr[k] = *reinterpret_cast<const float4*>(w + k * HID + c);
    float4 bb = *reinterpret_cast<const float4*>(b + c);

    int n0 = (blockIdx.x * 4 + wv) * NE_NPW;
    int n1 = min(n0 + NE_NPW, NNODES);
    for (int n = n0; n < n1; ++n) {
        const float4* xp = reinterpret_cast<const float4*>(x + (size_t)n * 32);
        float4 x0 = xp[0], x1 = xp[1], x2 = xp[2], x3 = xp[3];
        float4 x4 = xp[4], x5 = xp[5], x6 = xp[6], x7 = xp[7];
        float4 m = bb;
        FMA4(m, x0.x, wr[0]);  FMA4(m, x0.y, wr[1]);
        FMA4(m, x0.z, wr[2]);  FMA4(m, x0.w, wr[3]);
        FMA4(m, x1.x, wr[4]);  FMA4(m, x1.y, wr[5]);
        FMA4(m, x1.z, wr[6]);  FMA4(m, x1.w, wr[7]);
        FMA4(m, x2.x, wr[8]);  FMA4(m, x2.y, wr[9]);
        FMA4(m, x2.z, wr[10]); FMA4(m, x2.w, wr[11]);
        FMA4(m, x3.x, wr[12]); FMA4(m, x3.y, wr[13]);
        FMA4(m, x3.z, wr[14]); FMA4(m, x3.w, wr[15]);
        FMA4(m, x4.x, wr[16]); FMA4(m, x4.y, wr[17]);
        FMA4(m, x4.z, wr[18]); FMA4(m, x4.w, wr[19]);
        FMA4(m, x5.x, wr[20]); FMA4(m, x5.y, wr[21]);
        FMA4(m, x5.z, wr[22]); FMA4(m, x5.w, wr[23]);
        FMA4(m, x6.x, wr[24]); FMA4(m, x6.y, wr[25]);
        FMA4(m, x6.z, wr[26]); FMA4(m, x6.w, wr[27]);
        FMA4(m, x7.x, wr[28]); FMA4(m, x7.y, wr[29]);
        FMA4(m, x7.z, wr[30]); FMA4(m, x7.w, wr[31]);
        u16x4 o;
        o[0] = (unsigned short)f2b(m.x);
        o[1] = (unsigned short)f2b(m.y);
        o[2] = (unsigned short)f2b(m.z);
        o[3] = (unsigned short)f2b(m.w);
        *reinterpret_cast<u16x4*>(hb + (size_t)n * HID + c) = o;
    }
}

// ------------------------------------------------------------- CSR building
__global__ void deg_k(const int* __restrict__ ei, int* __restrict__ deg) {
    int e = blockIdx.x * 256 + threadIdx.x;
    if (e < NEDGES) atomicAdd(&deg[ei[NEDGES + e]], 1);
}

__global__ void scan1_k(const int* __restrict__ deg, int* __restrict__ partial,
                        int* __restrict__ btot) {
    __shared__ int s[256];
    int t = threadIdx.x;
    int gi = blockIdx.x * 256 + t;
    s[t] = (gi < NNODES) ? deg[gi] : 0;
    __syncthreads();
    for (int off = 1; off < 256; off <<= 1) {
        int u = (t >= off) ? s[t - off] : 0;
        __syncthreads();
        s[t] += u;
        __syncthreads();
    }
    if (gi < NNODES) partial[gi] = s[t];
    if (t == 255) btot[blockIdx.x] = s[255];
}

__global__ void scan2_k(int* __restrict__ btot, int nb) {
    __shared__ int s[256];
    int t = threadIdx.x;
    s[t] = (t < nb) ? btot[t] : 0;
    __syncthreads();
    for (int off = 1; off < 256; off <<= 1) {
        int u = (t >= off) ? s[t - off] : 0;
        __syncthreads();
        s[t] += u;
        __syncthreads();
    }
    btot[t] = s[t];
}

__global__ void scan3_k(const int* __restrict__ deg, const int* __restrict__ partial,
                        const int* __restrict__ btot, int* __restrict__ row_ptr,
                        int* __restrict__ cursor) {
    int gi = blockIdx.x * 256 + threadIdx.x;
    if (gi >= NNODES) return;
    int b = blockIdx.x;
    int incl = partial[gi] + (b ? btot[b - 1] : 0);
    int start = incl - deg[gi];
    row_ptr[gi] = start;
    cursor[gi] = start;
    if (gi == NNODES - 1) row_ptr[NNODES] = incl;
}

// fill: slot[e] = CSR position of edge e; srcs[pos] = src node (scatter).
__global__ void fill_k(const int* __restrict__ ei, int* __restrict__ cursor,
                       int* __restrict__ slot, int* __restrict__ srcs) {
    int e = blockIdx.x * 256 + threadIdx.x;
    if (e < NEDGES) {
        int d = ei[NEDGES + e];
        int pos = atomicAdd(&cursor[d], 1);
        slot[e] = pos;
        srcs[pos] = ei[e];
    }
}

// ---------- scatter the SMALL payload: eattr_s[slot[e]] = eattr[e] (fp32 64B)
__global__ void esort3_k(const float* __restrict__ eattr, const int* __restrict__ slot,
                         float* __restrict__ eattr_s) {
    int e = blockIdx.x * 64 + (threadIdx.x >> 2);   // 64 edges per block
    int q = threadIdx.x & 3;                        // 4 lanes per edge (16B each)
    if (e < NEDGES) {
        float4 v = reinterpret_cast<const float4*>(eattr + (size_t)e * 16)[q];
        reinterpret_cast<float4*>(eattr_s + (size_t)slot[e] * 16)[q] = v;
    }
}

// ---------------- one-time: ea_s[t] = bf16(eattr_s[t] @ ew + eb)
// Both sides streaming. 32 edges per wave (8 groups of 4).
#define EA_EPW 32
__global__ __launch_bounds__(256) void ea_k(const float* __restrict__ eattr_s,
                                            const float* __restrict__ ew,
                                            const float* __restrict__ ebias,
                                            short* __restrict__ ea_s) {
    int lane = threadIdx.x & 63, wv = threadIdx.x >> 6;
    int c = lane * 4;
    float4 w0  = *reinterpret_cast<const float4*>(ew + 0 * 256 + c);
    float4 w1  = *reinterpret_cast<const float4*>(ew + 1 * 256 + c);
    float4 w2  = *reinterpret_cast<const float4*>(ew + 2 * 256 + c);
    float4 w3  = *reinterpret_cast<const float4*>(ew + 3 * 256 + c);
    float4 w4  = *reinterpret_cast<const float4*>(ew + 4 * 256 + c);
    float4 w5  = *reinterpret_cast<const float4*>(ew + 5 * 256 + c);
    float4 w6  = *reinterpret_cast<const float4*>(ew + 6 * 256 + c);
    float4 w7  = *reinterpret_cast<const float4*>(ew + 7 * 256 + c);
    float4 w8  = *reinterpret_cast<const float4*>(ew + 8 * 256 + c);
    float4 w9  = *reinterpret_cast<const float4*>(ew + 9 * 256 + c);
    float4 w10 = *reinterpret_cast<const float4*>(ew + 10 * 256 + c);
    float4 w11 = *reinterpret_cast<const float4*>(ew + 11 * 256 + c);
    float4 w12 = *reinterpret_cast<const float4*>(ew + 12 * 256 + c);
    float4 w13 = *reinterpret_cast<const float4*>(ew + 13 * 256 + c);
    float4 w14 = *reinterpret_cast<const float4*>(ew + 14 * 256 + c);
    float4 w15 = *reinterpret_cast<const float4*>(ew + 15 * 256 + c);
    float4 ebv = *reinterpret_cast<const float4*>(ebias + c);

    int tw = (blockIdx.x * 4 + wv) * EA_EPW;
    int tend = min(tw + EA_EPW, NEDGES);
    for (int t0 = tw; t0 < tend; t0 += 4) {
        float4 q[4][4];
#pragma unroll
        for (int j = 0; j < 4; ++j) {
            const float4* ep = reinterpret_cast<const float4*>(eattr_s + (size_t)(t0 + j) * 16);
            q[j][0] = ep[0]; q[j][1] = ep[1]; q[j][2] = ep[2]; q[j][3] = ep[3];
        }
#pragma unroll
        for (int j = 0; j < 4; ++j) {
            float4 m = ebv;
            FMA4(m, q[j][0].x, w0);  FMA4(m, q[j][0].y, w1);
            FMA4(m, q[j][0].z, w2);  FMA4(m, q[j][0].w, w3);
            FMA4(m, q[j][1].x, w4);  FMA4(m, q[j][1].y, w5);
            FMA4(m, q[j][1].z, w6);  FMA4(m, q[j][1].w, w7);
            FMA4(m, q[j][2].x, w8);  FMA4(m, q[j][2].y, w9);
            FMA4(m, q[j][2].z, w10); FMA4(m, q[j][2].w, w11);
            FMA4(m, q[j][3].x, w12); FMA4(m, q[j][3].y, w13);
            FMA4(m, q[j][3].z, w14); FMA4(m, q[j][3].w, w15);
            u16x4 o;
            o[0] = (unsigned short)f2b(m.x);
            o[1] = (unsigned short)f2b(m.y);
            o[2] = (unsigned short)f2b(m.z);
            o[3] = (unsigned short)f2b(m.w);
            *reinterpret_cast<u16x4*>(ea_s + (size_t)(t0 + j) * HID + c) = o;
        }
    }
}

// --------------- BN prep: stats -> per-channel (scale, shift), re-zero stats
__global__ void bnprep_k(float* __restrict__ stats, const float* __restrict__ gamma,
                         const float* __restrict__ beta, float* __restrict__ ss) {
    int j = threadIdx.x;
    float mu  = stats[j] * (1.f / NNODES);
    float var = stats[256 + j] * (1.f / NNODES) - mu * mu;
    float sc  = rsqrtf(var + 1e-5f) * gamma[j];
    ss[j]       = sc;
    ss[256 + j] = beta[j] - mu * sc;
    stats[j] = 0.f;
    stats[256 + j] = 0.f;
}

// ------------------------------------------------- CSR aggregate, wave-per-node
template <bool BN>
__global__ __launch_bounds__(256) void agg_k(
    const short* __restrict__ y, const short* __restrict__ ea_s,
    const int* __restrict__ srcs, const int* __restrict__ row_ptr,
    const float* __restrict__ ss, short* __restrict__ out,
    float* __restrict__ stats) {
    if (!BN && blockIdx.x == 0) {
        stats[threadIdx.x] = 0.f;
        stats[threadIdx.x + 256] = 0.f;
    }
    int lane = threadIdx.x & 63, wv = threadIdx.x >> 6;
    int c = lane * 4;
    float sc0 = 1.f, sc1 = 1.f, sc2 = 1.f, sc3 = 1.f;
    float sh0 = 0.f, sh1 = 0.f, sh2 = 0.f, sh3 = 0.f;
    if (BN) {
        float4 scv = *reinterpret_cast<const float4*>(ss + c);
        float4 shv = *reinterpret_cast<const float4*>(ss + 256 + c);
        sc0 = scv.x; sc1 = scv.y; sc2 = scv.z; sc3 = scv.w;
        sh0 = shv.x; sh1 = shv.y; sh2 = shv.z; sh3 = shv.w;
    }
#define HVAL(v, i) (BN ? fmaxf(fmaf(b2f(v[i]), sc##i, sh##i), 0.f) : b2f(v[i]))
    int n = blockIdx.x * 4 + wv;          // grid exact: 12500*4 = 50000
    int beg = row_ptr[n], end = row_ptr[n + 1];
    u16x4 h4 = *reinterpret_cast<const u16x4*>(y + (size_t)n * HID + c);
    float a0 = HVAL(h4, 0), a1 = HVAL(h4, 1), a2 = HVAL(h4, 2), a3 = HVAL(h4, 3);

    for (int t = beg; t < end; t += 8) {
        int m = min(8, end - t);
        int ssrc[8];
        u16x4 ev[8], gv[8];
#pragma unroll
        for (int k = 0; k < 8; ++k)
            if (k < m) ssrc[k] = srcs[t + k];
#pragma unroll
        for (int k = 0; k < 8; ++k)
            if (k < m) {
                ev[k] = *reinterpret_cast<const u16x4*>(ea_s + (size_t)(t + k) * HID + c);
                gv[k] = *reinterpret_cast<const u16x4*>(y + (size_t)ssrc[k] * HID + c);
            }
#pragma unroll
        for (int k = 0; k < 8; ++k)
            if (k < m) {
                a0 += fmaxf(b2f(ev[k][0]) + HVAL(gv[k], 0), 0.f);
                a1 += fmaxf(b2f(ev[k][1]) + HVAL(gv[k], 1), 0.f);
                a2 += fmaxf(b2f(ev[k][2]) + HVAL(gv[k], 2), 0.f);
                a3 += fmaxf(b2f(ev[k][3]) + HVAL(gv[k], 3), 0.f);
            }
    }
#undef HVAL
    u16x4 o;
    o[0] = (unsigned short)f2b(a0);
    o[1] = (unsigned short)f2b(a1);
    o[2] = (unsigned short)f2b(a2);
    o[3] = (unsigned short)f2b(a3);
    *reinterpret_cast<u16x4*>(out + (size_t)n * HID + c) = o;
}

// ----------------------------------------------------------- bf16 MFMA GEMM
// C[M,256] = act(A@W + bias). BM=256 (4 waves x 64 rows), BN=64, K=256.
// (round-13 known-good version, reverted from the BM=128 experiment)
template <bool RELU, bool STATS>
__global__ __launch_bounds__(256, 3) void gemm_k(const short* __restrict__ A,
                                                 const short* __restrict__ wT,
                                                 const float* __restrict__ bias,
                                                 short* __restrict__ C,
                                                 float* __restrict__ stats, int M) {
    __shared__ short Bs[64 * 256]; // 32KB
    char* BsB = (char*)Bs;
    int wv = threadIdx.x >> 6, lane = threadIdx.x & 63;
    int lr = lane & 15, lg = lane >> 4;

    // XCD-chunked swizzle (grid 784 = 8 * 98)
    int bid = blockIdx.x;
    int sw = (bid & 7) * (gridDim.x >> 3) + (bid >> 3);
    int c0 = (sw & 3) * 64;
    int r0 = (sw >> 2) * 256 + wv * 64;

    const char* panel = (const char*)(wT + (size_t)c0 * 256);
    {
        float4 v[4];
#pragma unroll
        for (int it = 0; it < 4; ++it)
            v[it] = *reinterpret_cast<const float4*>(panel + (threadIdx.x + it * 256) * 16);
#pragma unroll
        for (int it = 0; it < 4; ++it) {
            int o = (threadIdx.x + it * 256) * 16;
            int n = o >> 9;
            *reinterpret_cast<float4*>(BsB + (o ^ ((n & 7) << 4))) = v[it];
        }
        float4 v2[4];
#pragma unroll
        for (int it = 4; it < 8; ++it)
            v2[it - 4] = *reinterpret_cast<const float4*>(panel + (threadIdx.x + it * 256) * 16);
#pragma unroll
        for (int it = 4; it < 8; ++it) {
            int o = (threadIdx.x + it * 256) * 16;
            int n = o >> 9;
            *reinterpret_cast<float4*>(BsB + (o ^ ((n & 7) << 4))) = v2[it - 4];
        }
    }

    const short* pA[4];
    bool gok[4];
#pragma unroll
    for (int f = 0; f < 4; ++f) {
        int r = r0 + f * 16 + lr;
        gok[f] = r < M;
        pA[f] = A + (size_t)r * 256 + lg * 8;
    }

    f32x4 acc[4][4] = {};
    bf16x8 aCur[4] = {}, aNxt[4] = {};
#pragma unroll
    for (int f = 0; f < 4; ++f)
        if (gok[f]) aCur[f] = *reinterpret_cast<const bf16x8*>(pA[f]);

    __syncthreads();

    for (int k0 = 0; k0 < 256; k0 += 32) {
        if (k0 < 224) {
#pragma unroll
            for (int f = 0; f < 4; ++f)
                if (gok[f]) aNxt[f] = *reinterpret_cast<const bf16x8*>(pA[f] + k0 + 32);
        }
#pragma unroll
        for (int cc = 0; cc < 4; ++cc) {
            int n = cc * 16 + lr;
            int kb = k0 * 2 + lg * 16;
            bf16x8 b = *reinterpret_cast<const bf16x8*>(
                BsB + ((n * 512 + (kb ^ ((n & 7) << 4)))));
#pragma unroll
            for (int f = 0; f < 4; ++f)
                acc[f][cc] = __builtin_amdgcn_mfma_f32_16x16x32_bf16(aCur[f], b, acc[f][cc], 0, 0, 0);
        }
#pragma unroll
        for (int f = 0; f < 4; ++f) aCur[f] = aNxt[f];
    }

    __syncthreads();
    char* S = BsB + wv * 8192;
#pragma unroll
    for (int cc = 0; cc < 4; ++cc) {
        int colL = cc * 16 + lr;
        float bi = bias[c0 + colL];
        float s = 0.f, ss2 = 0.f;
#pragma unroll
        for (int f = 0; f < 4; ++f)
#pragma unroll
            for (int i = 0; i < 4; ++i) {
                int rowL = f * 16 + lg * 4 + i;
                float v = acc[f][cc][i] + bi;
                if (RELU) v = fmaxf(v, 0.f);
                if (STATS && (r0 + rowL) < M) { s += v; ss2 = fmaf(v, v, ss2); }
                int byte = rowL * 128 + ((colL * 2) ^ ((rowL & 7) << 4));
                *reinterpret_cast<short*>(S + byte) = f2b(v);
            }
        if (STATS) {
            s   += __shfl_xor(s, 16);  ss2 += __shfl_xor(ss2, 16);
            s   += __shfl_xor(s, 32);  ss2 += __shfl_xor(ss2, 32);
            if (lg == 0) {
                atomicAdd(&stats[c0 + colL], s);
                atomicAdd(&stats[HID + c0 + colL], ss2);
            }
        }
    }
    asm volatile("s_waitcnt lgkmcnt(0)" ::: "memory");
#pragma unroll
    for (int j = 0; j < 8; ++j) {
        int rowL = j * 8 + (lane >> 3);
        int cb = (lane & 7) * 16;
        int byte = rowL * 128 + (cb ^ ((rowL & 7) << 4));
        int4 d = *reinterpret_cast<const int4*>(S + byte);
        int grow = r0 + rowL;
        if (grow < M)
            *reinterpret_cast<int4*>((char*)C + (size_t)grow * 512 + c0 * 2 + cb) = d;
    }
}

// ------------------------------------------------------------------ pool
#define PNB 64
__global__ void pool_k(const short* __restrict__ y, const int* __restrict__ batch,
                       const float* __restrict__ ss, float* __restrict__ g) {
    int j = threadIdx.x;
    float sc = ss[j], sh = ss[256 + j];
    int n0 = blockIdx.x * PNB;
    int n1 = min(n0 + PNB, NNODES);
    int cur = batch[n0];
    float acc = 0.f;
    for (int n = n0; n < n1; ++n) {
        int b = batch[n];
        if (b != cur) {
            atomicAdd(&g[(size_t)cur * HID + j], acc);
            acc = 0.f; cur = b;
        }
        float z = b2f((unsigned short)y[(size_t)n * HID + j]);
        acc += fmaxf(fmaf(z, sc, sh), 0.f);
    }
    atomicAdd(&g[(size_t)cur * HID + j], acc);
}

// ------------------------------------------------------------------ head
__global__ void head_k(const float* __restrict__ g, const float* __restrict__ w1,
                       const float* __restrict__ b1, const float* __restrict__ w2,
                       const float* __restrict__ b2, float* __restrict__ out) {
    int gi = blockIdx.x;
    int j  = threadIdx.x;
    __shared__ float gr[256];
    __shared__ float hid[128];
    gr[j]       = g[gi * 256 + j];
    gr[j + 128] = g[gi * 256 + 128 + j];
    __syncthreads();
    float acc = b1[j];
    for (int k = 0; k < 256; ++k) acc = fmaf(gr[k], w1[k * 128 + j], acc);
    hid[j] = fmaxf(acc, 0.f);
    __syncthreads();
    if (j < 12) {
        float o = b2[j];
#pragma unroll
        for (int k = 0; k < 128; ++k) o = fmaf(hid[k], w2[k * 12 + j], o);
        out[gi * 12 + j] = o;
    }
}

// ---------------------------------------------------------------- launch
extern "C" void kernel_launch(void* const* d_in, const int* in_sizes, int n_in,
                              void* d_out, int out_size, void* d_ws, size_t ws_size,
                              hipStream_t stream) {
    const float* x     = (const float*)d_in[0];
    const int*   ei    = (const int*)d_in[1];
    const int*   batch = (const int*)d_in[2];
    const float* eattr = (const float*)d_in[3];
    const float* nw    = (const float*)d_in[4];
    const float* nb    = (const float*)d_in[5];
    const float* ew    = (const float*)d_in[6];
    const float* eb    = (const float*)d_in[7];
    const float* w1    = (const float*)d_in[8];
    const float* b1    = (const float*)d_in[9];
    const float* w2    = (const float*)d_in[10];
    const float* b2    = (const float*)d_in[11];
    const float* gam   = (const float*)d_in[12];
    const float* bet   = (const float*)d_in[13];
    const float* hw1   = (const float*)d_in[14];
    const float* hb1   = (const float*)d_in[15];
    const float* hw2   = (const float*)d_in[16];
    const float* hb2   = (const float*)d_in[17];
    float* out = (float*)d_out;

    const size_t NH = (size_t)NNODES * HID;
    const size_t EH = (size_t)NEDGES * HID;
    size_t off = 0;
    char* base = (char*)d_ws;
    auto alloc = [&](size_t bytes) -> void* {
        void* p = base + off;
        off += (bytes + 255) & ~(size_t)255;
        return p;
    };
    short* y       = (short*)alloc(NH * 2);   // embed / gemm2 out (pre-BN z)
    short* a       = (short*)alloc(NH * 2);   // agg out
    short* bbuf    = (short*)alloc(NH * 2);   // gemm1 out
    short* wT      = (short*)alloc(8 * 65536 * 2);
    short* ea_s    = (short*)alloc(EH * 2);       // 153.6 MB, layer-invariant
    float* eattr_s = (float*)alloc((size_t)NEDGES * 16 * 4); // 19.2 MB slot-ordered
    int*   srcs    = (int*)alloc((size_t)NEDGES * 4);
    float* stats   = (float*)alloc(512 * 4);
    float* ssbuf   = (float*)alloc(512 * 4);  // (scale, shift)
    float* g       = (float*)alloc((size_t)NGRAPHS * HID * 4);
    int*   deg     = (int*)alloc((size_t)NNODES * 4);
    int*   partial = (int*)alloc((size_t)NNODES * 4);
    int*   btot    = (int*)alloc(256 * 4);
    int*   row_ptr = (int*)alloc((size_t)(NNODES + 1) * 4);
    int*   cursor  = (int*)alloc((size_t)NNODES * 4);
    int*   slot    = (int*)alloc((size_t)NEDGES * 4);

    wconv_k<<<dim3(256, 4), 256, 0, stream>>>(w1, wT);
    wconv_k<<<dim3(256, 4), 256, 0, stream>>>(w2, wT + 4 * 65536);
    node_embed_k<<<(NNODES + 4 * NE_NPW - 1) / (4 * NE_NPW), 256, 0, stream>>>(
        x, nw, nb, y);

    hipMemsetAsync(deg, 0, (size_t)NNODES * 4, stream);
    deg_k<<<(NEDGES + 255) / 256, 256, 0, stream>>>(ei, deg);
    const int NB = (NNODES + 255) / 256;
    scan1_k<<<NB, 256, 0, stream>>>(deg, partial, btot);
    scan2_k<<<1, 256, 0, stream>>>(btot, NB);
    scan3_k<<<NB, 256, 0, stream>>>(deg, partial, btot, row_ptr, cursor);
    fill_k<<<(NEDGES + 255) / 256, 256, 0, stream>>>(ei, cursor, slot, srcs);
    esort3_k<<<(NEDGES + 63) / 64, 256, 0, stream>>>(eattr, slot, eattr_s);
    ea_k<<<(NEDGES + 4 * EA_EPW - 1) / (4 * EA_EPW), 256, 0, stream>>>(
        eattr_s, ew, eb, ea_s);

    const int GG = ((NNODES + 255) / 256) * 4;   // 784, %8==0
    for (int l = 0; l < L; ++l) {
        if (l == 0) {
            agg_k<false><<<NNODES / 4, 256, 0, stream>>>(
                y, ea_s, srcs, row_ptr, nullptr, a, stats);
        } else {
            bnprep_k<<<1, 256, 0, stream>>>(stats, gam + (l - 1) * HID,
                                            bet + (l - 1) * HID, ssbuf);
            agg_k<true><<<NNODES / 4, 256, 0, stream>>>(
                y, ea_s, srcs, row_ptr, ssbuf, a, stats);
        }
        gemm_k<true, false><<<GG, 256, 0, stream>>>(
            a, wT + (size_t)l * 65536, b1 + l * HID, bbuf, nullptr, NNODES);
        gemm_k<false, true><<<GG, 256, 0, stream>>>(
            bbuf, wT + (size_t)(4 + l) * 65536, b2 + l * HID, y, stats, NNODES);
    }

    bnprep_k<<<1, 256, 0, stream>>>(stats, gam + 3 * HID, bet + 3 * HID, ssbuf);
    hipMemsetAsync(g, 0, (size_t)NGRAPHS * HID * 4, stream);
    pool_k<<<(NNODES + PNB - 1) / PNB, 256, 0, stream>>>(y, batch, ssbuf, g);
    head_k<<<NGRAPHS, 128, 0, stream>>>(g, hw1, hb1, hw2, hb2, out);
}